// Round 2
// baseline (560.498 us; speedup 1.0000x reference)
//
#include <hip/hip_runtime.h>
#include <math.h>

#define N_NODES 10000
#define N_EDGES 320000
#define DIM 256
#define ND ((size_t)N_NODES * DIM)

__device__ __forceinline__ float relu6f(float x) { return fminf(fmaxf(x, 0.f), 6.f); }

// ---------------- degree + in-degree histogram ----------------
__global__ void k_deg(const int* __restrict__ src, const int* __restrict__ dst,
                      float* __restrict__ deg, int* __restrict__ cnt) {
  int e = blockIdx.x * 256 + threadIdx.x;
  if (e < N_EDGES) {
    atomicAdd(&deg[src[e]], 1.f);
    atomicAdd(&deg[dst[e]], 1.f);
    atomicAdd(&cnt[dst[e]], 1);
  }
}

// ---------------- softmax over degrees -> center ----------------
__global__ void k_center(const float* __restrict__ deg, float* __restrict__ center) {
  __shared__ float red[1024];
  int tid = threadIdx.x;
  float m = -1e30f;
  for (int i = tid; i < N_NODES; i += 1024) m = fmaxf(m, deg[i]);
  red[tid] = m; __syncthreads();
  for (int off = 512; off > 0; off >>= 1) {
    if (tid < off) red[tid] = fmaxf(red[tid], red[tid + off]);
    __syncthreads();
  }
  float mx = red[0]; __syncthreads();
  float s = 0.f;
  for (int i = tid; i < N_NODES; i += 1024) s += expf(deg[i] - mx);
  red[tid] = s; __syncthreads();
  for (int off = 512; off > 0; off >>= 1) {
    if (tid < off) red[tid] += red[tid + off];
    __syncthreads();
  }
  float inv = 1.f / red[0];
  for (int i = tid; i < N_NODES; i += 1024) center[i] = expf(deg[i] - mx) * inv;
}

// ---------------- tiled fp32 GEMM: C = (A .* center?) @ W + bias ----------------
// A: [M x 256] row-major, W: [256 x 256] row-major, C: [M x 256]
// block tile 128x128, K-tile 16, 256 threads, 8x8 per thread (two 8x4 col chunks)
template <int MULC>
__global__ __launch_bounds__(256) void k_gemm(
    const float* __restrict__ A, const float* __restrict__ W0,
    const float* __restrict__ W1, const float* __restrict__ W2,
    const float* __restrict__ b0, const float* __restrict__ b1,
    const float* __restrict__ b2, const float* __restrict__ center,
    float* __restrict__ Cbase, int M) {
  const float* W = (blockIdx.z == 0) ? W0 : (blockIdx.z == 1) ? W1 : W2;
  const float* bias = (blockIdx.z == 0) ? b0 : (blockIdx.z == 1) ? b1 : b2;
  float* C = Cbase + (size_t)blockIdx.z * ND;

  __shared__ float As[16][128];
  __shared__ float Bs[16][128];
  int tid = threadIdx.x;
  int tx = tid & 15, ty = tid >> 4;
  int m0 = blockIdx.x * 128, n0 = blockIdx.y * 128;

  float acc[8][8];
#pragma unroll
  for (int i = 0; i < 8; i++)
#pragma unroll
    for (int j = 0; j < 8; j++) acc[i][j] = 0.f;

  for (int k0 = 0; k0 < 256; k0 += 16) {
#pragma unroll
    for (int i = 0; i < 2; i++) {
      int f = tid * 2 + i;
      int row = f >> 2, cb = (f & 3) * 4;
      int m = m0 + row;
      float4 a4 = make_float4(0.f, 0.f, 0.f, 0.f);
      if (m < M) {
        a4 = *(const float4*)(A + (size_t)m * 256 + k0 + cb);
        if (MULC) {
          float c = center[m];
          a4.x *= c; a4.y *= c; a4.z *= c; a4.w *= c;
        }
      }
      As[cb + 0][row] = a4.x; As[cb + 1][row] = a4.y;
      As[cb + 2][row] = a4.z; As[cb + 3][row] = a4.w;
    }
#pragma unroll
    for (int i = 0; i < 2; i++) {
      int f = tid * 2 + i;
      int kr = f >> 5, nc = (f & 31) * 4;
      *(float4*)&Bs[kr][nc] = *(const float4*)(W + (size_t)(k0 + kr) * 256 + n0 + nc);
    }
    __syncthreads();
#pragma unroll
    for (int kk = 0; kk < 16; kk++) {
      float a[8], b[8];
#pragma unroll
      for (int i = 0; i < 8; i++) a[i] = As[kk][ty * 8 + i];
#pragma unroll
      for (int j = 0; j < 4; j++) {
        b[j] = Bs[kk][tx * 4 + j];
        b[4 + j] = Bs[kk][64 + tx * 4 + j];
      }
#pragma unroll
      for (int i = 0; i < 8; i++)
#pragma unroll
        for (int j = 0; j < 8; j++) acc[i][j] = fmaf(a[i], b[j], acc[i][j]);
    }
    __syncthreads();
  }

  float bj[8];
#pragma unroll
  for (int j = 0; j < 4; j++) {
    bj[j] = bias[n0 + tx * 4 + j];
    bj[4 + j] = bias[n0 + 64 + tx * 4 + j];
  }
#pragma unroll
  for (int i = 0; i < 8; i++) {
    int m = m0 + ty * 8 + i;
    if (m >= M) continue;
    float4 c0, c1;
    c0.x = acc[i][0] + bj[0]; c0.y = acc[i][1] + bj[1];
    c0.z = acc[i][2] + bj[2]; c0.w = acc[i][3] + bj[3];
    c1.x = acc[i][4] + bj[4]; c1.y = acc[i][5] + bj[5];
    c1.z = acc[i][6] + bj[6]; c1.w = acc[i][7] + bj[7];
    *(float4*)(C + (size_t)m * 256 + n0 + tx * 4) = c0;
    *(float4*)(C + (size_t)m * 256 + n0 + 64 + tx * 4) = c1;
  }
}

// ---------------- per-edge attention scores ----------------
// wave per edge; 64 lanes cover the full 256-float row (float4 each);
// 16-lane groups reduce to per-head dot products.
__global__ void k_edge(const int* __restrict__ src, const int* __restrict__ dst,
                       const float* __restrict__ q, const float* __restrict__ k,
                       float* __restrict__ sbuf) {
  int lane = threadIdx.x & 63, wid = threadIdx.x >> 6;
  int e = blockIdx.x * 4 + wid;
  if (e >= N_EDGES) return;
  int sn = src[e], dn = dst[e];
  float4 kv = *(const float4*)(k + (size_t)sn * 256 + lane * 4);
  float4 qv = *(const float4*)(q + (size_t)dn * 256 + lane * 4);
  float p = kv.x * qv.x + kv.y * qv.y + kv.z * qv.z + kv.w * qv.w;
  p += __shfl_xor(p, 1);
  p += __shfl_xor(p, 2);
  p += __shfl_xor(p, 4);
  p += __shfl_xor(p, 8);
  if ((lane & 15) == 0) {
    float sc = p * 0.125f;
    sc = fminf(fmaxf(sc, -5.f), 5.f);
    sbuf[(size_t)e * 4 + (lane >> 4)] = expf(sc);
  }
}

// ---------------- exclusive scan of in-degree -> rowptr (single block) ----------------
__global__ void k_scan(const int* __restrict__ cnt, int* __restrict__ rowptr,
                       int* __restrict__ nextp) {
  __shared__ int tmp[1024];
  int tid = threadIdx.x;
  int carry = 0;
  for (int base = 0; base < N_NODES; base += 1024) {
    int i = base + tid;
    int v = (i < N_NODES) ? cnt[i] : 0;
    tmp[tid] = v; __syncthreads();
    for (int off = 1; off < 1024; off <<= 1) {
      int t = (tid >= off) ? tmp[tid - off] : 0;
      __syncthreads();
      tmp[tid] += t; __syncthreads();
    }
    if (i < N_NODES) {
      int excl = tmp[tid] - v + carry;
      rowptr[i] = excl;
      nextp[i] = excl;
    }
    carry += tmp[1023];
    __syncthreads();
  }
  if (tid == 0) rowptr[N_NODES] = carry;
}

// ---------------- CSR fill ----------------
__global__ void k_fill(const int* __restrict__ dst, int* __restrict__ nextp,
                       int* __restrict__ csr) {
  int e = blockIdx.x * 256 + threadIdx.x;
  if (e < N_EDGES) {
    int pos = atomicAdd(&nextp[dst[e]], 1);
    csr[pos] = e;
  }
}

// ---------------- aggregation: att[n,h,:] = sum_e s*vv[src] / sum_e s ----------------
// block per node, wave per head
__global__ void k_agg(const int* __restrict__ rowptr, const int* __restrict__ csr,
                      const int* __restrict__ src, const float* __restrict__ sbuf,
                      const float* __restrict__ vv, float* __restrict__ att) {
  int n = blockIdx.x;
  int head = threadIdx.x >> 6, lane = threadIdx.x & 63;
  int beg = rowptr[n], end = rowptr[n + 1];
  float acc = 0.f, z = 0.f;
  for (int i = beg; i < end; i++) {
    int e = csr[i];
    float sv = sbuf[(size_t)e * 4 + head];
    int sn = src[e];
    acc = fmaf(sv, vv[(size_t)sn * 256 + head * 64 + lane], acc);
    z += sv;
  }
  att[(size_t)n * 256 + head * 64 + lane] = acc / z;
}

// ---------------- BN stats (partial sums + atomics) ----------------
__global__ void k_bnstats(const float* __restrict__ o, float* __restrict__ bnsum,
                          float* __restrict__ bnsq) {
  int d = threadIdx.x;
  float s = 0.f, sq = 0.f;
  for (int r = blockIdx.x; r < N_NODES; r += gridDim.x) {
    float val = o[(size_t)r * 256 + d];
    s += val;
    sq = fmaf(val, val, sq);
  }
  atomicAdd(&bnsum[d], s);
  atomicAdd(&bnsq[d], sq);
}

__global__ void k_bnfinal(const float* __restrict__ bnsum, const float* __restrict__ bnsq,
                          const float* __restrict__ gamma, const float* __restrict__ beta,
                          float* __restrict__ scale, float* __restrict__ shift) {
  int d = threadIdx.x;
  float mean = bnsum[d] * (1.f / N_NODES);
  float var = bnsq[d] * (1.f / N_NODES) - mean * mean;
  float istd = rsqrtf(var + 1e-5f);
  float sc = gamma[d] * istd;
  scale[d] = sc;
  shift[d] = beta[d] - mean * sc;
}

__global__ void k_bnapply(const float* __restrict__ o, const float* __restrict__ scale,
                          const float* __restrict__ shift, float* __restrict__ x) {
  size_t i = ((size_t)blockIdx.x * 256 + threadIdx.x) * 4;
  int d = (int)(i & 255);
  float4 ov = *(const float4*)(o + i);
  float4 xv;
  xv.x = relu6f(fmaf(ov.x, scale[d + 0], shift[d + 0]));
  xv.y = relu6f(fmaf(ov.y, scale[d + 1], shift[d + 1]));
  xv.z = relu6f(fmaf(ov.z, scale[d + 2], shift[d + 2]));
  xv.w = relu6f(fmaf(ov.w, scale[d + 3], shift[d + 3]));
  *(float4*)(x + i) = xv;
}

// ---------------- fused SE block ----------------
// wave per node: hidden = relu6(x@W1+b1) (lane = hidden unit), share via LDS,
// then se = hidden@W2+b2, out = hswish(se)*x + v  (4 outputs per lane)
__global__ __launch_bounds__(256) void k_se(
    const float* __restrict__ x, const float* __restrict__ W1,
    const float* __restrict__ b1, const float* __restrict__ W2,
    const float* __restrict__ b2, const float* __restrict__ v,
    float* __restrict__ out) {
  __shared__ float xl[4][256];
  __shared__ float hl[4][64];
  int lane = threadIdx.x & 63, wid = threadIdx.x >> 6;
  int n = blockIdx.x * 4 + wid;
  *(float4*)&xl[wid][lane * 4] = *(const float4*)(x + (size_t)n * 256 + lane * 4);
  __syncthreads();
  float acc = b1[lane];
#pragma unroll 8
  for (int d = 0; d < 256; d++) acc = fmaf(xl[wid][d], W1[d * 64 + lane], acc);
  hl[wid][lane] = relu6f(acc);
  __syncthreads();
#pragma unroll
  for (int m = 0; m < 4; m++) {
    int d = m * 64 + lane;
    float se = b2[d];
#pragma unroll 8
    for (int h = 0; h < 64; h++) se = fmaf(hl[wid][h], W2[h * 256 + d], se);
    float hs = se * relu6f(se + 3.f) * (1.f / 6.f);
    size_t idx = (size_t)n * 256 + d;
    out[idx] = fmaf(hs, xl[wid][d], v[idx]);
  }
}

extern "C" void kernel_launch(void* const* d_in, const int* in_sizes, int n_in,
                              void* d_out, int out_size, void* d_ws, size_t ws_size,
                              hipStream_t stream) {
  const float* v     = (const float*)d_in[0];
  const float* WQ    = (const float*)d_in[1];
  const float* bQ    = (const float*)d_in[2];
  const float* WK    = (const float*)d_in[3];
  const float* bK    = (const float*)d_in[4];
  const float* WV    = (const float*)d_in[5];
  const float* bV    = (const float*)d_in[6];
  const float* Wo    = (const float*)d_in[7];
  const float* bo    = (const float*)d_in[8];
  const float* W1    = (const float*)d_in[9];
  const float* b1    = (const float*)d_in[10];
  const float* W2    = (const float*)d_in[11];
  const float* b2    = (const float*)d_in[12];
  const float* gamma = (const float*)d_in[13];
  const float* beta  = (const float*)d_in[14];
  const int* srcI    = (const int*)d_in[15];
  const int* dstI    = (const int*)d_in[16];
  float* out = (float*)d_out;

  char* w = (char*)d_ws;
  size_t off = 0;
  auto take = [&](size_t bytes) {
    size_t o = off;
    off += (bytes + 255) & ~(size_t)255;
    return o;
  };
  float* deg    = (float*)(w + take(N_NODES * 4));
  float* center = (float*)(w + take(N_NODES * 4));
  float* qkv    = (float*)(w + take(3 * ND * 4));   // q | k | vv
  float* sbuf   = (float*)(w + take((size_t)N_EDGES * 4 * 4));
  float* bnsum  = (float*)(w + take(256 * 4));
  float* bnsq   = (float*)(w + take(256 * 4));
  float* scale  = (float*)(w + take(256 * 4));
  float* shift  = (float*)(w + take(256 * 4));
  int* cnt      = (int*)(w + take(N_NODES * 4));
  int* rowptr   = (int*)(w + take((N_NODES + 1) * 4));
  int* nextp    = (int*)(w + take(N_NODES * 4));
  int* csr      = (int*)(w + take((size_t)N_EDGES * 4));

  float* q  = qkv;
  float* k  = qkv + ND;
  float* vv = qkv + 2 * ND;
  float* att = q;       // reuse (q dead after k_edge)
  float* o   = k;       // reuse (k dead after k_edge)
  float* x   = vv;      // reuse (vv dead after k_agg)

  hipMemsetAsync(deg, 0, N_NODES * 4, stream);
  hipMemsetAsync(cnt, 0, N_NODES * 4, stream);
  hipMemsetAsync(bnsum, 0, 256 * 4, stream);
  hipMemsetAsync(bnsq, 0, 256 * 4, stream);

  k_deg<<<dim3((N_EDGES + 255) / 256), dim3(256), 0, stream>>>(srcI, dstI, deg, cnt);
  k_center<<<dim3(1), dim3(1024), 0, stream>>>(deg, center);

  // q,k,vv = (v*center) @ {WQ,WK,WV} + b
  k_gemm<1><<<dim3(79, 2, 3), dim3(256), 0, stream>>>(
      v, WQ, WK, WV, bQ, bK, bV, center, qkv, N_NODES);

  k_edge<<<dim3(N_EDGES / 4), dim3(256), 0, stream>>>(srcI, dstI, q, k, sbuf);

  k_scan<<<dim3(1), dim3(1024), 0, stream>>>(cnt, rowptr, nextp);
  k_fill<<<dim3((N_EDGES + 255) / 256), dim3(256), 0, stream>>>(dstI, nextp, csr);
  k_agg<<<dim3(N_NODES), dim3(256), 0, stream>>>(rowptr, csr, srcI, sbuf, vv, att);

  // o = att @ Wo + bo
  k_gemm<0><<<dim3(79, 2, 1), dim3(256), 0, stream>>>(
      att, Wo, Wo, Wo, bo, bo, bo, nullptr, o, N_NODES);

  k_bnstats<<<dim3(240), dim3(256), 0, stream>>>(o, bnsum, bnsq);
  k_bnfinal<<<dim3(1), dim3(256), 0, stream>>>(bnsum, bnsq, gamma, beta, scale, shift);
  k_bnapply<<<dim3(N_NODES * 256 / 1024), dim3(256), 0, stream>>>(o, scale, shift, x);

  k_se<<<dim3(N_NODES / 4), dim3(256), 0, stream>>>(x, W1, b1, W2, b2, v, out);
}

// Round 3
// 422.434 us; speedup vs baseline: 1.3268x; 1.3268x over previous
//
#include <hip/hip_runtime.h>
#include <math.h>

#define N_NODES 10000
#define N_EDGES 320000
#define DIM 256
#define ND ((size_t)N_NODES * DIM)

__device__ __forceinline__ float relu6f(float x) { return fminf(fmaxf(x, 0.f), 6.f); }

// ---------------- degree histograms ----------------
__global__ void k_deg(const int* __restrict__ src, const int* __restrict__ dst,
                      int* __restrict__ outc, int* __restrict__ inc) {
  int e = blockIdx.x * 256 + threadIdx.x;
  if (e < N_EDGES) {
    atomicAdd(&outc[src[e]], 1);
    atomicAdd(&inc[dst[e]], 1);
  }
}

// ---------------- softmax over degrees -> center ----------------
__global__ void k_center(const int* __restrict__ inc, const int* __restrict__ outc,
                         float* __restrict__ center) {
  __shared__ float red[1024];
  int tid = threadIdx.x;
  float m = -1e30f;
  for (int i = tid; i < N_NODES; i += 1024) m = fmaxf(m, (float)(inc[i] + outc[i]));
  red[tid] = m; __syncthreads();
  for (int off = 512; off > 0; off >>= 1) {
    if (tid < off) red[tid] = fmaxf(red[tid], red[tid + off]);
    __syncthreads();
  }
  float mx = red[0]; __syncthreads();
  float s = 0.f;
  for (int i = tid; i < N_NODES; i += 1024) s += expf((float)(inc[i] + outc[i]) - mx);
  red[tid] = s; __syncthreads();
  for (int off = 512; off > 0; off >>= 1) {
    if (tid < off) red[tid] += red[tid + off];
    __syncthreads();
  }
  float inv = 1.f / red[0];
  for (int i = tid; i < N_NODES; i += 1024)
    center[i] = expf((float)(inc[i] + outc[i]) - mx) * inv;
}

// ---------------- tiled fp32 GEMM: C = (A .* center?) @ W + bias ----------------
template <int MULC>
__global__ __launch_bounds__(256) void k_gemm(
    const float* __restrict__ A, const float* __restrict__ W0,
    const float* __restrict__ W1, const float* __restrict__ W2,
    const float* __restrict__ b0, const float* __restrict__ b1,
    const float* __restrict__ b2, const float* __restrict__ center,
    float* __restrict__ Cbase, int M) {
  const float* W = (blockIdx.z == 0) ? W0 : (blockIdx.z == 1) ? W1 : W2;
  const float* bias = (blockIdx.z == 0) ? b0 : (blockIdx.z == 1) ? b1 : b2;
  float* C = Cbase + (size_t)blockIdx.z * ND;

  __shared__ float As[16][128];
  __shared__ float Bs[16][128];
  int tid = threadIdx.x;
  int tx = tid & 15, ty = tid >> 4;
  int m0 = blockIdx.x * 128, n0 = blockIdx.y * 128;

  float acc[8][8];
#pragma unroll
  for (int i = 0; i < 8; i++)
#pragma unroll
    for (int j = 0; j < 8; j++) acc[i][j] = 0.f;

  for (int k0 = 0; k0 < 256; k0 += 16) {
#pragma unroll
    for (int i = 0; i < 2; i++) {
      int f = tid * 2 + i;
      int row = f >> 2, cb = (f & 3) * 4;
      int m = m0 + row;
      float4 a4 = make_float4(0.f, 0.f, 0.f, 0.f);
      if (m < M) {
        a4 = *(const float4*)(A + (size_t)m * 256 + k0 + cb);
        if (MULC) {
          float c = center[m];
          a4.x *= c; a4.y *= c; a4.z *= c; a4.w *= c;
        }
      }
      As[cb + 0][row] = a4.x; As[cb + 1][row] = a4.y;
      As[cb + 2][row] = a4.z; As[cb + 3][row] = a4.w;
    }
#pragma unroll
    for (int i = 0; i < 2; i++) {
      int f = tid * 2 + i;
      int kr = f >> 5, nc = (f & 31) * 4;
      *(float4*)&Bs[kr][nc] = *(const float4*)(W + (size_t)(k0 + kr) * 256 + n0 + nc);
    }
    __syncthreads();
#pragma unroll
    for (int kk = 0; kk < 16; kk++) {
      float a[8], b[8];
#pragma unroll
      for (int i = 0; i < 8; i++) a[i] = As[kk][ty * 8 + i];
#pragma unroll
      for (int j = 0; j < 4; j++) {
        b[j] = Bs[kk][tx * 4 + j];
        b[4 + j] = Bs[kk][64 + tx * 4 + j];
      }
#pragma unroll
      for (int i = 0; i < 8; i++)
#pragma unroll
        for (int j = 0; j < 8; j++) acc[i][j] = fmaf(a[i], b[j], acc[i][j]);
    }
    __syncthreads();
  }

  float bj[8];
#pragma unroll
  for (int j = 0; j < 4; j++) {
    bj[j] = bias[n0 + tx * 4 + j];
    bj[4 + j] = bias[n0 + 64 + tx * 4 + j];
  }
#pragma unroll
  for (int i = 0; i < 8; i++) {
    int m = m0 + ty * 8 + i;
    if (m >= M) continue;
    float4 c0, c1;
    c0.x = acc[i][0] + bj[0]; c0.y = acc[i][1] + bj[1];
    c0.z = acc[i][2] + bj[2]; c0.w = acc[i][3] + bj[3];
    c1.x = acc[i][4] + bj[4]; c1.y = acc[i][5] + bj[5];
    c1.z = acc[i][6] + bj[6]; c1.w = acc[i][7] + bj[7];
    *(float4*)(C + (size_t)m * 256 + n0 + tx * 4) = c0;
    *(float4*)(C + (size_t)m * 256 + n0 + 64 + tx * 4) = c1;
  }
}

// ---------------- exclusive scan (wave-shuffle version) ----------------
__global__ void k_scan(const int* __restrict__ cnt, int* __restrict__ rowptr,
                       int* __restrict__ nextp) {
  __shared__ int wsum[16];
  __shared__ int carry_s;
  int tid = threadIdx.x, lane = tid & 63, wid = tid >> 6;
  if (tid == 0) carry_s = 0;
  __syncthreads();
  for (int base = 0; base < N_NODES; base += 1024) {
    int i = base + tid;
    int v = (i < N_NODES) ? cnt[i] : 0;
    int x = v;
#pragma unroll
    for (int off = 1; off < 64; off <<= 1) {
      int t = __shfl_up(x, off);
      if (lane >= off) x += t;
    }
    if (lane == 63) wsum[wid] = x;
    __syncthreads();
    if (wid == 0 && lane < 16) {
      int wv = wsum[lane];
#pragma unroll
      for (int off = 1; off < 16; off <<= 1) {
        int t = __shfl_up(wv, off);
        if (lane >= off) wv += t;
      }
      wsum[lane] = wv;
    }
    __syncthreads();
    int carry = carry_s;
    int wadd = (wid > 0) ? wsum[wid - 1] : 0;
    int excl = carry + wadd + x - v;
    if (i < N_NODES) {
      rowptr[i] = excl;
      nextp[i] = excl;
    }
    __syncthreads();
    if (tid == 1023) carry_s = excl + v;
    __syncthreads();
  }
  if (tid == 0) rowptr[N_NODES] = carry_s;
}

// ---------------- CSR fill: store src node id per slot ----------------
__global__ void k_fill(const int* __restrict__ src, const int* __restrict__ dst,
                       int* __restrict__ nextp, int* __restrict__ csr_src) {
  int e = blockIdx.x * 256 + threadIdx.x;
  if (e < N_EDGES) {
    int pos = atomicAdd(&nextp[dst[e]], 1);
    csr_src[pos] = src[e];
  }
}

// ---------------- fused edge-score + aggregation ----------------
// block per dst node, wave per head; lane covers the head's 64 dims.
// 4-way edge unroll keeps 4 independent gathers in flight.
__global__ __launch_bounds__(256) void k_edgeagg(
    const int* __restrict__ rowptr, const int* __restrict__ csr_src,
    const float* __restrict__ q, const float* __restrict__ kmat,
    const float* __restrict__ vvmat, float* __restrict__ att) {
  int n = blockIdx.x;
  int head = threadIdx.x >> 6, lane = threadIdx.x & 63;
  int base = head * 64 + lane;
  int beg = rowptr[n], end = rowptr[n + 1];
  float qv = q[(size_t)n * 256 + base];
  float acc = 0.f, z = 0.f;
  int i = beg;
  for (; i + 4 <= end; i += 4) {
    int s0 = csr_src[i], s1 = csr_src[i + 1], s2 = csr_src[i + 2], s3 = csr_src[i + 3];
    float k0 = kmat[(size_t)s0 * 256 + base];
    float k1 = kmat[(size_t)s1 * 256 + base];
    float k2 = kmat[(size_t)s2 * 256 + base];
    float k3 = kmat[(size_t)s3 * 256 + base];
    float p0 = k0 * qv, p1 = k1 * qv, p2 = k2 * qv, p3 = k3 * qv;
#pragma unroll
    for (int off = 1; off < 64; off <<= 1) {
      p0 += __shfl_xor(p0, off);
      p1 += __shfl_xor(p1, off);
      p2 += __shfl_xor(p2, off);
      p3 += __shfl_xor(p3, off);
    }
    float e0 = __expf(fminf(fmaxf(p0 * 0.125f, -5.f), 5.f));
    float e1 = __expf(fminf(fmaxf(p1 * 0.125f, -5.f), 5.f));
    float e2 = __expf(fminf(fmaxf(p2 * 0.125f, -5.f), 5.f));
    float e3 = __expf(fminf(fmaxf(p3 * 0.125f, -5.f), 5.f));
    float v0 = vvmat[(size_t)s0 * 256 + base];
    float v1 = vvmat[(size_t)s1 * 256 + base];
    float v2 = vvmat[(size_t)s2 * 256 + base];
    float v3 = vvmat[(size_t)s3 * 256 + base];
    acc = fmaf(e0, v0, acc);
    acc = fmaf(e1, v1, acc);
    acc = fmaf(e2, v2, acc);
    acc = fmaf(e3, v3, acc);
    z += (e0 + e1) + (e2 + e3);
  }
  for (; i < end; ++i) {
    int sE = csr_src[i];
    float kv = kmat[(size_t)sE * 256 + base];
    float p = kv * qv;
#pragma unroll
    for (int off = 1; off < 64; off <<= 1) p += __shfl_xor(p, off);
    float e0 = __expf(fminf(fmaxf(p * 0.125f, -5.f), 5.f));
    acc = fmaf(e0, vvmat[(size_t)sE * 256 + base], acc);
    z += e0;
  }
  att[(size_t)n * 256 + base] = acc / z;
}

// ---------------- BN stats (partial sums + atomics) ----------------
__global__ void k_bnstats(const float* __restrict__ o, float* __restrict__ bnsum,
                          float* __restrict__ bnsq) {
  int d = threadIdx.x;
  float s = 0.f, sq = 0.f;
  for (int r = blockIdx.x; r < N_NODES; r += gridDim.x) {
    float val = o[(size_t)r * 256 + d];
    s += val;
    sq = fmaf(val, val, sq);
  }
  atomicAdd(&bnsum[d], s);
  atomicAdd(&bnsq[d], sq);
}

__global__ void k_bnfinal(const float* __restrict__ bnsum, const float* __restrict__ bnsq,
                          const float* __restrict__ gamma, const float* __restrict__ beta,
                          float* __restrict__ scale, float* __restrict__ shift) {
  int d = threadIdx.x;
  float mean = bnsum[d] * (1.f / N_NODES);
  float var = bnsq[d] * (1.f / N_NODES) - mean * mean;
  float istd = rsqrtf(var + 1e-5f);
  float sc = gamma[d] * istd;
  scale[d] = sc;
  shift[d] = beta[d] - mean * sc;
}

// ---------------- fused BN-apply + SE block ----------------
// wave per node: x = relu6(o*scale+shift) built in LDS, hidden = relu6(x@W1+b1),
// se = hidden@W2+b2, out = hswish(se)*x + v
__global__ __launch_bounds__(256) void k_se(
    const float* __restrict__ o, const float* __restrict__ scale,
    const float* __restrict__ shift, const float* __restrict__ W1,
    const float* __restrict__ b1, const float* __restrict__ W2,
    const float* __restrict__ b2, const float* __restrict__ v,
    float* __restrict__ out) {
  __shared__ float xl[4][256];
  __shared__ float hl[4][64];
  int lane = threadIdx.x & 63, wid = threadIdx.x >> 6;
  int n = blockIdx.x * 4 + wid;
  int d0 = lane * 4;
  float4 ov = *(const float4*)(o + (size_t)n * 256 + d0);
  float4 xv;
  xv.x = relu6f(fmaf(ov.x, scale[d0 + 0], shift[d0 + 0]));
  xv.y = relu6f(fmaf(ov.y, scale[d0 + 1], shift[d0 + 1]));
  xv.z = relu6f(fmaf(ov.z, scale[d0 + 2], shift[d0 + 2]));
  xv.w = relu6f(fmaf(ov.w, scale[d0 + 3], shift[d0 + 3]));
  *(float4*)&xl[wid][d0] = xv;
  __syncthreads();
  float acc = b1[lane];
#pragma unroll 8
  for (int d = 0; d < 256; d++) acc = fmaf(xl[wid][d], W1[d * 64 + lane], acc);
  hl[wid][lane] = relu6f(acc);
  __syncthreads();
#pragma unroll
  for (int m = 0; m < 4; m++) {
    int d = m * 64 + lane;
    float se = b2[d];
#pragma unroll 8
    for (int h = 0; h < 64; h++) se = fmaf(hl[wid][h], W2[h * 256 + d], se);
    float hs = se * relu6f(se + 3.f) * (1.f / 6.f);
    size_t idx = (size_t)n * 256 + d;
    out[idx] = fmaf(hs, xl[wid][d], v[idx]);
  }
}

extern "C" void kernel_launch(void* const* d_in, const int* in_sizes, int n_in,
                              void* d_out, int out_size, void* d_ws, size_t ws_size,
                              hipStream_t stream) {
  const float* v     = (const float*)d_in[0];
  const float* WQ    = (const float*)d_in[1];
  const float* bQ    = (const float*)d_in[2];
  const float* WK    = (const float*)d_in[3];
  const float* bK    = (const float*)d_in[4];
  const float* WV    = (const float*)d_in[5];
  const float* bV    = (const float*)d_in[6];
  const float* Wo    = (const float*)d_in[7];
  const float* bo    = (const float*)d_in[8];
  const float* W1    = (const float*)d_in[9];
  const float* b1    = (const float*)d_in[10];
  const float* W2    = (const float*)d_in[11];
  const float* b2    = (const float*)d_in[12];
  const float* gamma = (const float*)d_in[13];
  const float* beta  = (const float*)d_in[14];
  const int* srcI    = (const int*)d_in[15];
  const int* dstI    = (const int*)d_in[16];
  float* out = (float*)d_out;

  char* w = (char*)d_ws;
  size_t off = 0;
  auto take = [&](size_t bytes) {
    size_t o = off;
    off += (bytes + 255) & ~(size_t)255;
    return o;
  };
  int* inc      = (int*)(w + take(N_NODES * 4));
  int* outc     = (int*)(w + take(N_NODES * 4));
  float* center = (float*)(w + take(N_NODES * 4));
  float* qkv    = (float*)(w + take(3 * ND * 4));   // q | k | vv
  float* bnsum  = (float*)(w + take(256 * 4));
  float* bnsq   = (float*)(w + take(256 * 4));
  float* scale  = (float*)(w + take(256 * 4));
  float* shift  = (float*)(w + take(256 * 4));
  int* rowptr   = (int*)(w + take((N_NODES + 1) * 4));
  int* nextp    = (int*)(w + take(N_NODES * 4));
  int* csr_src  = (int*)(w + take((size_t)N_EDGES * 4));

  float* q  = qkv;
  float* k  = qkv + ND;
  float* vv = qkv + 2 * ND;
  float* att = q;       // reuse (q dead after k_edgeagg)
  float* o   = k;       // reuse (k dead after k_edgeagg)

  hipMemsetAsync(inc, 0, N_NODES * 4, stream);
  hipMemsetAsync(outc, 0, N_NODES * 4, stream);
  hipMemsetAsync(bnsum, 0, 256 * 4, stream);
  hipMemsetAsync(bnsq, 0, 256 * 4, stream);

  k_deg<<<dim3((N_EDGES + 255) / 256), dim3(256), 0, stream>>>(srcI, dstI, outc, inc);
  k_center<<<dim3(1), dim3(1024), 0, stream>>>(inc, outc, center);
  k_scan<<<dim3(1), dim3(1024), 0, stream>>>(inc, rowptr, nextp);
  k_fill<<<dim3((N_EDGES + 255) / 256), dim3(256), 0, stream>>>(srcI, dstI, nextp, csr_src);

  // q,k,vv = (v*center) @ {WQ,WK,WV} + b
  k_gemm<1><<<dim3(79, 2, 3), dim3(256), 0, stream>>>(
      v, WQ, WK, WV, bQ, bK, bV, center, qkv, N_NODES);

  k_edgeagg<<<dim3(N_NODES), dim3(256), 0, stream>>>(rowptr, csr_src, q, k, vv, att);

  // o = att @ Wo + bo
  k_gemm<0><<<dim3(79, 2, 1), dim3(256), 0, stream>>>(
      att, Wo, Wo, Wo, bo, bo, bo, nullptr, o, N_NODES);

  k_bnstats<<<dim3(240), dim3(256), 0, stream>>>(o, bnsum, bnsq);
  k_bnfinal<<<dim3(1), dim3(256), 0, stream>>>(bnsum, bnsq, gamma, beta, scale, shift);

  k_se<<<dim3(N_NODES / 4), dim3(256), 0, stream>>>(o, scale, shift, W1, b1, W2, b2, v, out);
}

// Round 4
// 372.751 us; speedup vs baseline: 1.5037x; 1.1333x over previous
//
#include <hip/hip_runtime.h>
#include <math.h>

#define N_NODES 10000
#define N_EDGES 320000
#define DIM 256
#define ND ((size_t)N_NODES * DIM)

typedef float f32x4 __attribute__((ext_vector_type(4)));
typedef short s16x8 __attribute__((ext_vector_type(8)));

__device__ __forceinline__ float relu6f(float x) { return fminf(fmaxf(x, 0.f), 6.f); }

__device__ __forceinline__ short f2bf(float x) {
  unsigned u = __builtin_bit_cast(unsigned, x);
  unsigned r = (u + 0x7fffu + ((u >> 16) & 1u)) >> 16;
  return (short)r;
}
__device__ __forceinline__ float bf2f(short b) {
  unsigned u = ((unsigned)(unsigned short)b) << 16;
  return __builtin_bit_cast(float, u);
}

// ---------------- degree histograms ----------------
__global__ void k_deg(const int* __restrict__ src, const int* __restrict__ dst,
                      int* __restrict__ outc, int* __restrict__ inc) {
  int e = blockIdx.x * 256 + threadIdx.x;
  if (e < N_EDGES) {
    atomicAdd(&outc[src[e]], 1);
    atomicAdd(&inc[dst[e]], 1);
  }
}

// ---------------- softmax over degrees -> center ----------------
__global__ void k_center(const int* __restrict__ inc, const int* __restrict__ outc,
                         float* __restrict__ center) {
  __shared__ float red[1024];
  int tid = threadIdx.x;
  float m = -1e30f;
  for (int i = tid; i < N_NODES; i += 1024) m = fmaxf(m, (float)(inc[i] + outc[i]));
  red[tid] = m; __syncthreads();
  for (int off = 512; off > 0; off >>= 1) {
    if (tid < off) red[tid] = fmaxf(red[tid], red[tid + off]);
    __syncthreads();
  }
  float mx = red[0]; __syncthreads();
  float s = 0.f;
  for (int i = tid; i < N_NODES; i += 1024) s += expf((float)(inc[i] + outc[i]) - mx);
  red[tid] = s; __syncthreads();
  for (int off = 512; off > 0; off >>= 1) {
    if (tid < off) red[tid] += red[tid + off];
    __syncthreads();
  }
  float inv = 1.f / red[0];
  for (int i = tid; i < N_NODES; i += 1024)
    center[i] = expf((float)(inc[i] + outc[i]) - mx) * inv;
}

// ---------------- W transpose + bf16 hi/lo split ----------------
// in: W [256k x 256n] fp32 row-major; out: Wt_hi/Wt_lo [256n x 256k] bf16
__global__ __launch_bounds__(256) void k_wsplit(
    const float* __restrict__ Wa, const float* __restrict__ Wb,
    const float* __restrict__ Wc, const float* __restrict__ Wd,
    short* __restrict__ Whi, short* __restrict__ Wlo) {
  const float* W = (blockIdx.y == 0) ? Wa : (blockIdx.y == 1) ? Wb
                   : (blockIdx.y == 2) ? Wc : Wd;
  short* hi = Whi + (size_t)blockIdx.y * 65536;
  short* lo = Wlo + (size_t)blockIdx.y * 65536;
  __shared__ float tile[64][65];
  int t = threadIdx.x;
  int tk = (blockIdx.x >> 2) * 64, tn = (blockIdx.x & 3) * 64;
  int r = t >> 4, c4 = (t & 15) * 4;
#pragma unroll
  for (int p = 0; p < 4; p++) {
    float4 v4 = *(const float4*)(W + (size_t)(tk + p * 16 + r) * 256 + tn + c4);
    tile[p * 16 + r][c4 + 0] = v4.x;
    tile[p * 16 + r][c4 + 1] = v4.y;
    tile[p * 16 + r][c4 + 2] = v4.z;
    tile[p * 16 + r][c4 + 3] = v4.w;
  }
  __syncthreads();
  int nl = t >> 2, q = t & 3;
  s16x8 h0, h1, l0, l1;
#pragma unroll
  for (int j = 0; j < 8; j++) {
    float x = tile[q * 16 + j][nl];
    short hb = f2bf(x);
    h0[j] = hb; l0[j] = f2bf(x - bf2f(hb));
  }
#pragma unroll
  for (int j = 0; j < 8; j++) {
    float x = tile[q * 16 + 8 + j][nl];
    short hb = f2bf(x);
    h1[j] = hb; l1[j] = f2bf(x - bf2f(hb));
  }
  size_t base = (size_t)(tn + nl) * 256 + tk + q * 16;
  *(s16x8*)(hi + base) = h0;
  *(s16x8*)(hi + base + 8) = h1;
  *(s16x8*)(lo + base) = l0;
  *(s16x8*)(lo + base + 8) = l1;
}

// ---------------- bf16-split MFMA GEMM ----------------
// C = (A .* center?) @ W + bias, via A_hi@W_hi + A_hi@W_lo + A_lo@W_hi
// A: [M x 256] fp32; Wt: [z][256n x 256k] bf16 transposed; C: [M x 256]
// block: 256 thr = 4 waves (2m x 2n), tile 64m x 128n, K-step 32
template <int MULC>
__global__ __launch_bounds__(256) void k_gemm_mfma(
    const float* __restrict__ A, const short* __restrict__ Whi,
    const short* __restrict__ Wlo, const float* __restrict__ b0,
    const float* __restrict__ b1, const float* __restrict__ b2,
    const float* __restrict__ center, float* __restrict__ Cbase, int M) {
  const float* bias = (blockIdx.z == 0) ? b0 : (blockIdx.z == 1) ? b1 : b2;
  const short* whi = Whi + (size_t)blockIdx.z * 65536;
  const short* wlo = Wlo + (size_t)blockIdx.z * 65536;
  float* C = Cbase + (size_t)blockIdx.z * ND;

  __shared__ __align__(16) short Ah[64][40];
  __shared__ __align__(16) short Al[64][40];
  __shared__ __align__(16) short Bh[128][40];
  __shared__ __align__(16) short Bl[128][40];

  int tid = threadIdx.x;
  int lane = tid & 63, wid = tid >> 6;
  int wm = wid >> 1, wn = wid & 1;
  int m0 = blockIdx.x * 64;
  int n0g = blockIdx.y * 128;

  f32x4 acc[2][4];
#pragma unroll
  for (int i = 0; i < 2; i++)
#pragma unroll
    for (int j = 0; j < 4; j++) acc[i][j] = (f32x4){0.f, 0.f, 0.f, 0.f};

  // staging coords
  int sa_row = tid >> 2, sa_seg = tid & 3;          // A: 64 rows x 4 segs of 8
  int sb_row = tid >> 1, sb_seg = tid & 1;          // B: 128 rows x 2 segs of 16
  float cmul = 1.f;
  if (MULC) {
    int m = m0 + sa_row;
    cmul = (m < M) ? center[m] : 0.f;
  }

  for (int k0 = 0; k0 < 256; k0 += 32) {
    __syncthreads();
    // ---- stage A (fp32 -> hi/lo bf16) ----
    {
      int m = m0 + sa_row;
      float4 x0 = make_float4(0.f, 0.f, 0.f, 0.f), x1 = x0;
      if (m < M) {
        const float* ap = A + (size_t)m * 256 + k0 + sa_seg * 8;
        x0 = *(const float4*)ap;
        x1 = *(const float4*)(ap + 4);
        if (MULC) {
          x0.x *= cmul; x0.y *= cmul; x0.z *= cmul; x0.w *= cmul;
          x1.x *= cmul; x1.y *= cmul; x1.z *= cmul; x1.w *= cmul;
        }
      }
      s16x8 h, l;
      float xs[8] = {x0.x, x0.y, x0.z, x0.w, x1.x, x1.y, x1.z, x1.w};
#pragma unroll
      for (int j = 0; j < 8; j++) {
        short hb = f2bf(xs[j]);
        h[j] = hb; l[j] = f2bf(xs[j] - bf2f(hb));
      }
      *(s16x8*)&Ah[sa_row][sa_seg * 8] = h;
      *(s16x8*)&Al[sa_row][sa_seg * 8] = l;
    }
    // ---- stage B (already bf16, transposed) ----
    {
      size_t gb = (size_t)(n0g + sb_row) * 256 + k0 + sb_seg * 16;
      *(s16x8*)&Bh[sb_row][sb_seg * 16] = *(const s16x8*)(whi + gb);
      *(s16x8*)&Bh[sb_row][sb_seg * 16 + 8] = *(const s16x8*)(whi + gb + 8);
      *(s16x8*)&Bl[sb_row][sb_seg * 16] = *(const s16x8*)(wlo + gb);
      *(s16x8*)&Bl[sb_row][sb_seg * 16 + 8] = *(const s16x8*)(wlo + gb + 8);
    }
    __syncthreads();
    // ---- fragments + MFMA ----
    int arow0 = wm * 32 + (lane & 15);
    int kc = (lane >> 4) * 8;
    s16x8 ah[2], al[2], bh[4], bl[4];
#pragma unroll
    for (int mf = 0; mf < 2; mf++) {
      ah[mf] = *(const s16x8*)&Ah[arow0 + mf * 16][kc];
      al[mf] = *(const s16x8*)&Al[arow0 + mf * 16][kc];
    }
    int brow0 = wn * 64 + (lane & 15);
#pragma unroll
    for (int nf = 0; nf < 4; nf++) {
      bh[nf] = *(const s16x8*)&Bh[brow0 + nf * 16][kc];
      bl[nf] = *(const s16x8*)&Bl[brow0 + nf * 16][kc];
    }
#pragma unroll
    for (int mf = 0; mf < 2; mf++)
#pragma unroll
      for (int nf = 0; nf < 4; nf++) {
        acc[mf][nf] = __builtin_amdgcn_mfma_f32_16x16x32_bf16(ah[mf], bh[nf], acc[mf][nf], 0, 0, 0);
        acc[mf][nf] = __builtin_amdgcn_mfma_f32_16x16x32_bf16(al[mf], bh[nf], acc[mf][nf], 0, 0, 0);
        acc[mf][nf] = __builtin_amdgcn_mfma_f32_16x16x32_bf16(ah[mf], bl[nf], acc[mf][nf], 0, 0, 0);
      }
  }

  // ---- epilogue: C = acc + bias ----
  int colq = lane & 15, rowq = (lane >> 4) * 4;
#pragma unroll
  for (int mf = 0; mf < 2; mf++) {
#pragma unroll
    for (int nf = 0; nf < 4; nf++) {
      int n = wn * 64 + nf * 16 + colq;
      float bv = bias[n0g + n];
#pragma unroll
      for (int j = 0; j < 4; j++) {
        int m = m0 + wm * 32 + mf * 16 + rowq + j;
        if (m < M) C[(size_t)m * 256 + n0g + n] = acc[mf][nf][j] + bv;
      }
    }
  }
}

// ---------------- exclusive scan (wave-shuffle version) ----------------
__global__ void k_scan(const int* __restrict__ cnt, int* __restrict__ rowptr,
                       int* __restrict__ nextp) {
  __shared__ int wsum[16];
  __shared__ int carry_s;
  int tid = threadIdx.x, lane = tid & 63, wid = tid >> 6;
  if (tid == 0) carry_s = 0;
  __syncthreads();
  for (int base = 0; base < N_NODES; base += 1024) {
    int i = base + tid;
    int v = (i < N_NODES) ? cnt[i] : 0;
    int x = v;
#pragma unroll
    for (int off = 1; off < 64; off <<= 1) {
      int t = __shfl_up(x, off);
      if (lane >= off) x += t;
    }
    if (lane == 63) wsum[wid] = x;
    __syncthreads();
    if (wid == 0 && lane < 16) {
      int wv = wsum[lane];
#pragma unroll
      for (int off = 1; off < 16; off <<= 1) {
        int t = __shfl_up(wv, off);
        if (lane >= off) wv += t;
      }
      wsum[lane] = wv;
    }
    __syncthreads();
    int carry = carry_s;
    int wadd = (wid > 0) ? wsum[wid - 1] : 0;
    int excl = carry + wadd + x - v;
    if (i < N_NODES) {
      rowptr[i] = excl;
      nextp[i] = excl;
    }
    __syncthreads();
    if (tid == 1023) carry_s = excl + v;
    __syncthreads();
  }
  if (tid == 0) rowptr[N_NODES] = carry_s;
}

// ---------------- CSR fill: store src node id per slot ----------------
__global__ void k_fill(const int* __restrict__ src, const int* __restrict__ dst,
                       int* __restrict__ nextp, int* __restrict__ csr_src) {
  int e = blockIdx.x * 256 + threadIdx.x;
  if (e < N_EDGES) {
    int pos = atomicAdd(&nextp[dst[e]], 1);
    csr_src[pos] = src[e];
  }
}

// ---------------- fused edge-score + aggregation ----------------
__global__ __launch_bounds__(256) void k_edgeagg(
    const int* __restrict__ rowptr, const int* __restrict__ csr_src,
    const float* __restrict__ q, const float* __restrict__ kmat,
    const float* __restrict__ vvmat, float* __restrict__ att) {
  int n = blockIdx.x;
  int head = threadIdx.x >> 6, lane = threadIdx.x & 63;
  int base = head * 64 + lane;
  int beg = rowptr[n], end = rowptr[n + 1];
  float qv = q[(size_t)n * 256 + base];
  float acc = 0.f, z = 0.f;
  int i = beg;
  for (; i + 4 <= end; i += 4) {
    int s0 = csr_src[i], s1 = csr_src[i + 1], s2 = csr_src[i + 2], s3 = csr_src[i + 3];
    float k0 = kmat[(size_t)s0 * 256 + base];
    float k1 = kmat[(size_t)s1 * 256 + base];
    float k2 = kmat[(size_t)s2 * 256 + base];
    float k3 = kmat[(size_t)s3 * 256 + base];
    float p0 = k0 * qv, p1 = k1 * qv, p2 = k2 * qv, p3 = k3 * qv;
#pragma unroll
    for (int off = 1; off < 64; off <<= 1) {
      p0 += __shfl_xor(p0, off);
      p1 += __shfl_xor(p1, off);
      p2 += __shfl_xor(p2, off);
      p3 += __shfl_xor(p3, off);
    }
    float e0 = __expf(fminf(fmaxf(p0 * 0.125f, -5.f), 5.f));
    float e1 = __expf(fminf(fmaxf(p1 * 0.125f, -5.f), 5.f));
    float e2 = __expf(fminf(fmaxf(p2 * 0.125f, -5.f), 5.f));
    float e3 = __expf(fminf(fmaxf(p3 * 0.125f, -5.f), 5.f));
    float v0 = vvmat[(size_t)s0 * 256 + base];
    float v1 = vvmat[(size_t)s1 * 256 + base];
    float v2 = vvmat[(size_t)s2 * 256 + base];
    float v3 = vvmat[(size_t)s3 * 256 + base];
    acc = fmaf(e0, v0, acc);
    acc = fmaf(e1, v1, acc);
    acc = fmaf(e2, v2, acc);
    acc = fmaf(e3, v3, acc);
    z += (e0 + e1) + (e2 + e3);
  }
  for (; i < end; ++i) {
    int sE = csr_src[i];
    float kv = kmat[(size_t)sE * 256 + base];
    float p = kv * qv;
#pragma unroll
    for (int off = 1; off < 64; off <<= 1) p += __shfl_xor(p, off);
    float e0 = __expf(fminf(fmaxf(p * 0.125f, -5.f), 5.f));
    acc = fmaf(e0, vvmat[(size_t)sE * 256 + base], acc);
    z += e0;
  }
  att[(size_t)n * 256 + base] = acc / z;
}

// ---------------- BN stats (partial sums + atomics) ----------------
__global__ void k_bnstats(const float* __restrict__ o, float* __restrict__ bnsum,
                          float* __restrict__ bnsq) {
  int d = threadIdx.x;
  float s = 0.f, sq = 0.f;
  for (int r = blockIdx.x; r < N_NODES; r += gridDim.x) {
    float val = o[(size_t)r * 256 + d];
    s += val;
    sq = fmaf(val, val, sq);
  }
  atomicAdd(&bnsum[d], s);
  atomicAdd(&bnsq[d], sq);
}

__global__ void k_bnfinal(const float* __restrict__ bnsum, const float* __restrict__ bnsq,
                          const float* __restrict__ gamma, const float* __restrict__ beta,
                          float* __restrict__ scale, float* __restrict__ shift) {
  int d = threadIdx.x;
  float mean = bnsum[d] * (1.f / N_NODES);
  float var = bnsq[d] * (1.f / N_NODES) - mean * mean;
  float istd = rsqrtf(var + 1e-5f);
  float sc = gamma[d] * istd;
  scale[d] = sc;
  shift[d] = beta[d] - mean * sc;
}

// ---------------- fused BN-apply + SE block ----------------
__global__ __launch_bounds__(256) void k_se(
    const float* __restrict__ o, const float* __restrict__ scale,
    const float* __restrict__ shift, const float* __restrict__ W1,
    const float* __restrict__ b1, const float* __restrict__ W2,
    const float* __restrict__ b2, const float* __restrict__ v,
    float* __restrict__ out) {
  __shared__ float xl[4][256];
  __shared__ float hl[4][64];
  int lane = threadIdx.x & 63, wid = threadIdx.x >> 6;
  int n = blockIdx.x * 4 + wid;
  int d0 = lane * 4;
  float4 ov = *(const float4*)(o + (size_t)n * 256 + d0);
  float4 xv;
  xv.x = relu6f(fmaf(ov.x, scale[d0 + 0], shift[d0 + 0]));
  xv.y = relu6f(fmaf(ov.y, scale[d0 + 1], shift[d0 + 1]));
  xv.z = relu6f(fmaf(ov.z, scale[d0 + 2], shift[d0 + 2]));
  xv.w = relu6f(fmaf(ov.w, scale[d0 + 3], shift[d0 + 3]));
  *(float4*)&xl[wid][d0] = xv;
  __syncthreads();
  float acc = b1[lane];
#pragma unroll 8
  for (int d = 0; d < 256; d++) acc = fmaf(xl[wid][d], W1[d * 64 + lane], acc);
  hl[wid][lane] = relu6f(acc);
  __syncthreads();
#pragma unroll
  for (int m = 0; m < 4; m++) {
    int d = m * 64 + lane;
    float se = b2[d];
#pragma unroll 8
    for (int h = 0; h < 64; h++) se = fmaf(hl[wid][h], W2[h * 256 + d], se);
    float hs = se * relu6f(se + 3.f) * (1.f / 6.f);
    size_t idx = (size_t)n * 256 + d;
    out[idx] = fmaf(hs, xl[wid][d], v[idx]);
  }
}

extern "C" void kernel_launch(void* const* d_in, const int* in_sizes, int n_in,
                              void* d_out, int out_size, void* d_ws, size_t ws_size,
                              hipStream_t stream) {
  const float* v     = (const float*)d_in[0];
  const float* WQ    = (const float*)d_in[1];
  const float* bQ    = (const float*)d_in[2];
  const float* WK    = (const float*)d_in[3];
  const float* bK    = (const float*)d_in[4];
  const float* WV    = (const float*)d_in[5];
  const float* bV    = (const float*)d_in[6];
  const float* Wo    = (const float*)d_in[7];
  const float* bo    = (const float*)d_in[8];
  const float* W1    = (const float*)d_in[9];
  const float* b1    = (const float*)d_in[10];
  const float* W2    = (const float*)d_in[11];
  const float* b2    = (const float*)d_in[12];
  const float* gamma = (const float*)d_in[13];
  const float* beta  = (const float*)d_in[14];
  const int* srcI    = (const int*)d_in[15];
  const int* dstI    = (const int*)d_in[16];
  float* out = (float*)d_out;

  char* w = (char*)d_ws;
  size_t off = 0;
  auto take = [&](size_t bytes) {
    size_t o = off;
    off += (bytes + 255) & ~(size_t)255;
    return o;
  };
  int* inc      = (int*)(w + take(N_NODES * 4));
  int* outc     = (int*)(w + take(N_NODES * 4));
  float* center = (float*)(w + take(N_NODES * 4));
  float* qkv    = (float*)(w + take(3 * ND * 4));   // q | k | vv
  float* bnsum  = (float*)(w + take(256 * 4));
  float* bnsq   = (float*)(w + take(256 * 4));
  float* scale  = (float*)(w + take(256 * 4));
  float* shift  = (float*)(w + take(256 * 4));
  int* rowptr   = (int*)(w + take((N_NODES + 1) * 4));
  int* nextp    = (int*)(w + take(N_NODES * 4));
  int* csr_src  = (int*)(w + take((size_t)N_EDGES * 4));
  short* Wt_hi  = (short*)(w + take((size_t)4 * 65536 * 2));
  short* Wt_lo  = (short*)(w + take((size_t)4 * 65536 * 2));

  float* q  = qkv;
  float* k  = qkv + ND;
  float* vv = qkv + 2 * ND;
  float* att = q;       // reuse (q dead after k_edgeagg)
  float* o   = k;       // reuse (k dead after k_edgeagg)

  hipMemsetAsync(inc, 0, N_NODES * 4, stream);
  hipMemsetAsync(outc, 0, N_NODES * 4, stream);
  hipMemsetAsync(bnsum, 0, 256 * 4, stream);
  hipMemsetAsync(bnsq, 0, 256 * 4, stream);

  k_wsplit<<<dim3(16, 4), dim3(256), 0, stream>>>(WQ, WK, WV, Wo, Wt_hi, Wt_lo);
  k_deg<<<dim3((N_EDGES + 255) / 256), dim3(256), 0, stream>>>(srcI, dstI, outc, inc);
  k_center<<<dim3(1), dim3(1024), 0, stream>>>(inc, outc, center);
  k_scan<<<dim3(1), dim3(1024), 0, stream>>>(inc, rowptr, nextp);
  k_fill<<<dim3((N_EDGES + 255) / 256), dim3(256), 0, stream>>>(srcI, dstI, nextp, csr_src);

  // q,k,vv = (v*center) @ {WQ,WK,WV} + b   (bf16-split MFMA)
  k_gemm_mfma<1><<<dim3(157, 2, 3), dim3(256), 0, stream>>>(
      v, Wt_hi, Wt_lo, bQ, bK, bV, center, qkv, N_NODES);

  k_edgeagg<<<dim3(N_NODES), dim3(256), 0, stream>>>(rowptr, csr_src, q, k, vv, att);

  // o = att @ Wo + bo  (Wo is slot 3 of Wt)
  k_gemm_mfma<0><<<dim3(157, 2, 1), dim3(256), 0, stream>>>(
      att, Wt_hi + (size_t)3 * 65536, Wt_lo + (size_t)3 * 65536,
      bo, bo, bo, nullptr, o, N_NODES);

  k_bnstats<<<dim3(240), dim3(256), 0, stream>>>(o, bnsum, bnsq);
  k_bnfinal<<<dim3(1), dim3(256), 0, stream>>>(bnsum, bnsq, gamma, beta, scale, shift);

  k_se<<<dim3(N_NODES / 4), dim3(256), 0, stream>>>(o, scale, shift, W1, b1, W2, b2, v, out);
}

// Round 6
// 317.899 us; speedup vs baseline: 1.7631x; 1.1725x over previous
//
#include <hip/hip_runtime.h>
#include <math.h>

#define N_NODES 10000
#define N_EDGES 320000
#define DIM 256
#define ND ((size_t)N_NODES * DIM)

typedef float f32x4 __attribute__((ext_vector_type(4)));
typedef short s16x8 __attribute__((ext_vector_type(8)));

__device__ __forceinline__ float relu6f(float x) { return fminf(fmaxf(x, 0.f), 6.f); }

__device__ __forceinline__ short f2bf(float x) {
  unsigned u = __builtin_bit_cast(unsigned, x);
  unsigned r = (u + 0x7fffu + ((u >> 16) & 1u)) >> 16;
  return (short)r;
}
__device__ __forceinline__ float bf2f(short b) {
  unsigned u = ((unsigned)(unsigned short)b) << 16;
  return __builtin_bit_cast(float, u);
}
__device__ __forceinline__ float bflo(unsigned u) {
  return __builtin_bit_cast(float, u << 16);
}
__device__ __forceinline__ float bfhi(unsigned u) {
  return __builtin_bit_cast(float, u & 0xffff0000u);
}

// ---------------- degree histograms ----------------
__global__ void k_deg(const int* __restrict__ src, const int* __restrict__ dst,
                      int* __restrict__ outc, int* __restrict__ inc) {
  int e = blockIdx.x * 256 + threadIdx.x;
  if (e < N_EDGES) {
    atomicAdd(&outc[src[e]], 1);
    atomicAdd(&inc[dst[e]], 1);
  }
}

// ---------------- sum of exp(deg) in double (no max pass needed) ----------------
__global__ void k_expsum(const int* __restrict__ inc, const int* __restrict__ outc,
                         double* __restrict__ Zd) {
  int i = blockIdx.x * 256 + threadIdx.x;
  int lane = threadIdx.x & 63;
  double e = 0.0;
  if (i < N_NODES) e = exp((double)(inc[i] + outc[i]));
#pragma unroll
  for (int off = 1; off < 64; off <<= 1) e += __shfl_xor(e, off);
  if (lane == 0) atomicAdd(Zd, e);
}

// ---------------- W transpose + bf16 hi/lo split ----------------
__global__ __launch_bounds__(256) void k_wsplit(
    const float* __restrict__ Wa, const float* __restrict__ Wb,
    const float* __restrict__ Wc, const float* __restrict__ Wd,
    short* __restrict__ Whi, short* __restrict__ Wlo) {
  const float* W = (blockIdx.y == 0) ? Wa : (blockIdx.y == 1) ? Wb
                   : (blockIdx.y == 2) ? Wc : Wd;
  short* hi = Whi + (size_t)blockIdx.y * 65536;
  short* lo = Wlo + (size_t)blockIdx.y * 65536;
  __shared__ float tile[64][65];
  int t = threadIdx.x;
  int tk = (blockIdx.x >> 2) * 64, tn = (blockIdx.x & 3) * 64;
  int r = t >> 4, c4 = (t & 15) * 4;
#pragma unroll
  for (int p = 0; p < 4; p++) {
    float4 v4 = *(const float4*)(W + (size_t)(tk + p * 16 + r) * 256 + tn + c4);
    tile[p * 16 + r][c4 + 0] = v4.x;
    tile[p * 16 + r][c4 + 1] = v4.y;
    tile[p * 16 + r][c4 + 2] = v4.z;
    tile[p * 16 + r][c4 + 3] = v4.w;
  }
  __syncthreads();
  int nl = t >> 2, q = t & 3;
  s16x8 h0, h1, l0, l1;
#pragma unroll
  for (int j = 0; j < 8; j++) {
    float x = tile[q * 16 + j][nl];
    short hb = f2bf(x);
    h0[j] = hb; l0[j] = f2bf(x - bf2f(hb));
  }
#pragma unroll
  for (int j = 0; j < 8; j++) {
    float x = tile[q * 16 + 8 + j][nl];
    short hb = f2bf(x);
    h1[j] = hb; l1[j] = f2bf(x - bf2f(hb));
  }
  size_t base = (size_t)(tn + nl) * 256 + tk + q * 16;
  *(s16x8*)(hi + base) = h0;
  *(s16x8*)(hi + base + 8) = h1;
  *(s16x8*)(lo + base) = l0;
  *(s16x8*)(lo + base + 8) = l1;
}

// ---------------- bf16-split MFMA GEMM ----------------
// KVMODE=1: z=0 -> Q fp32 [N][256]; z=1 -> KV bf16 cols 0..255; z=2 -> KV bf16 cols 256..511
// KVMODE=0: z=0 -> Cbase fp32
template <int MULC, int KVMODE>
__global__ __launch_bounds__(256) void k_gemm_mfma(
    const float* __restrict__ A, const short* __restrict__ Whi,
    const short* __restrict__ Wlo, const float* __restrict__ b0,
    const float* __restrict__ b1, const float* __restrict__ b2,
    const int* __restrict__ inc, const int* __restrict__ outc,
    const float* __restrict__ logzf, float* __restrict__ Qout,
    unsigned short* __restrict__ KVout, float* __restrict__ Cbase, int M) {
  const float* bias = (blockIdx.z == 0) ? b0 : (blockIdx.z == 1) ? b1 : b2;
  const short* whi = Whi + (size_t)blockIdx.z * 65536;
  const short* wlo = Wlo + (size_t)blockIdx.z * 65536;

  __shared__ __align__(16) short Ah[64][40];
  __shared__ __align__(16) short Al[64][40];
  __shared__ __align__(16) short Bh[128][40];
  __shared__ __align__(16) short Bl[128][40];

  int tid = threadIdx.x;
  int lane = tid & 63, wid = tid >> 6;
  int wm = wid >> 1, wn = wid & 1;
  int m0 = blockIdx.x * 64;
  int n0g = blockIdx.y * 128;

  f32x4 acc[2][4];
#pragma unroll
  for (int i = 0; i < 2; i++)
#pragma unroll
    for (int j = 0; j < 4; j++) acc[i][j] = (f32x4){0.f, 0.f, 0.f, 0.f};

  int sa_row = tid >> 2, sa_seg = tid & 3;
  int sb_row = tid >> 1, sb_seg = tid & 1;
  float cmul = 1.f;
  if (MULC) {
    int m = m0 + sa_row;
    cmul = (m < M) ? __expf((float)(inc[m] + outc[m]) - logzf[0]) : 0.f;
  }

  for (int k0 = 0; k0 < 256; k0 += 32) {
    __syncthreads();
    {
      int m = m0 + sa_row;
      float4 x0 = make_float4(0.f, 0.f, 0.f, 0.f), x1 = x0;
      if (m < M) {
        const float* ap = A + (size_t)m * 256 + k0 + sa_seg * 8;
        x0 = *(const float4*)ap;
        x1 = *(const float4*)(ap + 4);
        if (MULC) {
          x0.x *= cmul; x0.y *= cmul; x0.z *= cmul; x0.w *= cmul;
          x1.x *= cmul; x1.y *= cmul; x1.z *= cmul; x1.w *= cmul;
        }
      }
      s16x8 h, l;
      float xs[8] = {x0.x, x0.y, x0.z, x0.w, x1.x, x1.y, x1.z, x1.w};
#pragma unroll
      for (int j = 0; j < 8; j++) {
        short hb = f2bf(xs[j]);
        h[j] = hb; l[j] = f2bf(xs[j] - bf2f(hb));
      }
      *(s16x8*)&Ah[sa_row][sa_seg * 8] = h;
      *(s16x8*)&Al[sa_row][sa_seg * 8] = l;
    }
    {
      size_t gb = (size_t)(n0g + sb_row) * 256 + k0 + sb_seg * 16;
      *(s16x8*)&Bh[sb_row][sb_seg * 16] = *(const s16x8*)(whi + gb);
      *(s16x8*)&Bh[sb_row][sb_seg * 16 + 8] = *(const s16x8*)(whi + gb + 8);
      *(s16x8*)&Bl[sb_row][sb_seg * 16] = *(const s16x8*)(wlo + gb);
      *(s16x8*)&Bl[sb_row][sb_seg * 16 + 8] = *(const s16x8*)(wlo + gb + 8);
    }
    __syncthreads();
    int arow0 = wm * 32 + (lane & 15);
    int kc = (lane >> 4) * 8;
    s16x8 ah[2], al[2], bh[4], bl[4];
#pragma unroll
    for (int mf = 0; mf < 2; mf++) {
      ah[mf] = *(const s16x8*)&Ah[arow0 + mf * 16][kc];
      al[mf] = *(const s16x8*)&Al[arow0 + mf * 16][kc];
    }
    int brow0 = wn * 64 + (lane & 15);
#pragma unroll
    for (int nf = 0; nf < 4; nf++) {
      bh[nf] = *(const s16x8*)&Bh[brow0 + nf * 16][kc];
      bl[nf] = *(const s16x8*)&Bl[brow0 + nf * 16][kc];
    }
#pragma unroll
    for (int mf = 0; mf < 2; mf++)
#pragma unroll
      for (int nf = 0; nf < 4; nf++) {
        acc[mf][nf] = __builtin_amdgcn_mfma_f32_16x16x32_bf16(ah[mf], bh[nf], acc[mf][nf], 0, 0, 0);
        acc[mf][nf] = __builtin_amdgcn_mfma_f32_16x16x32_bf16(al[mf], bh[nf], acc[mf][nf], 0, 0, 0);
        acc[mf][nf] = __builtin_amdgcn_mfma_f32_16x16x32_bf16(ah[mf], bl[nf], acc[mf][nf], 0, 0, 0);
      }
  }

  int colq = lane & 15, rowq = (lane >> 4) * 4;
  bool isq = (KVMODE == 0) || (blockIdx.z == 0);
  int kvoff = (blockIdx.z == 1) ? 0 : 256;
#pragma unroll
  for (int mf = 0; mf < 2; mf++) {
#pragma unroll
    for (int nf = 0; nf < 4; nf++) {
      int n = wn * 64 + nf * 16 + colq;
      float bv = bias[n0g + n];
#pragma unroll
      for (int j = 0; j < 4; j++) {
        int m = m0 + wm * 32 + mf * 16 + rowq + j;
        if (m >= M) continue;
        float val = acc[mf][nf][j] + bv;
        if (isq) {
          float* C = (KVMODE == 1) ? Qout : Cbase;
          C[(size_t)m * 256 + n0g + n] = val;
        } else {
          KVout[(size_t)m * 512 + kvoff + n0g + n] = (unsigned short)f2bf(val);
        }
      }
    }
  }
}

// ---------------- exclusive scan + logZ ----------------
__global__ void k_scan(const int* __restrict__ cnt, int* __restrict__ rowptr,
                       int* __restrict__ nextp, const double* __restrict__ Zd,
                       float* __restrict__ logzf) {
  __shared__ int wsum[16];
  __shared__ int carry_s;
  int tid = threadIdx.x, lane = tid & 63, wid = tid >> 6;
  if (tid == 0) {
    carry_s = 0;
    logzf[0] = (float)log(Zd[0]);
  }
  __syncthreads();
  for (int base = 0; base < N_NODES; base += 1024) {
    int i = base + tid;
    int v = (i < N_NODES) ? cnt[i] : 0;
    int x = v;
#pragma unroll
    for (int off = 1; off < 64; off <<= 1) {
      int t = __shfl_up(x, off);
      if (lane >= off) x += t;
    }
    if (lane == 63) wsum[wid] = x;
    __syncthreads();
    if (wid == 0 && lane < 16) {
      int wv = wsum[lane];
#pragma unroll
      for (int off = 1; off < 16; off <<= 1) {
        int t = __shfl_up(wv, off);
        if (lane >= off) wv += t;
      }
      wsum[lane] = wv;
    }
    __syncthreads();
    int carry = carry_s;
    int wadd = (wid > 0) ? wsum[wid - 1] : 0;
    int excl = carry + wadd + x - v;
    if (i < N_NODES) {
      rowptr[i] = excl;
      nextp[i] = excl;
    }
    __syncthreads();
    if (tid == 1023) carry_s = excl + v;
    __syncthreads();
  }
  if (tid == 0) rowptr[N_NODES] = carry_s;
}

// ---------------- CSR fill ----------------
__global__ void k_fill(const int* __restrict__ src, const int* __restrict__ dst,
                       int* __restrict__ nextp, int* __restrict__ csr_src) {
  int e = blockIdx.x * 256 + threadIdx.x;
  if (e < N_EDGES) {
    int pos = atomicAdd(&nextp[dst[e]], 1);
    csr_src[pos] = src[e];
  }
}

// ---------------- fused edge-score + aggregation (bf16 kv, wave per node) ----------------
// lane covers dims 4*lane..4*lane+3 (all 4 heads per wave); head h = lanes 16h..16h+15
__global__ __launch_bounds__(256) void k_edgeagg(
    const int* __restrict__ rowptr, const int* __restrict__ csr_src,
    const float* __restrict__ q, const unsigned short* __restrict__ kv,
    float* __restrict__ att) {
  int lane = threadIdx.x & 63, wid = threadIdx.x >> 6;
  int n = blockIdx.x * 4 + wid;
  int beg = rowptr[n], end = rowptr[n + 1];
  float4 qv = *(const float4*)(q + (size_t)n * 256 + lane * 4);
  const unsigned short* kvl = kv + lane * 4;
  float a0 = 0.f, a1 = 0.f, a2 = 0.f, a3 = 0.f, z = 0.f;

#define EDGE_BODY(SRC)                                                        \
  {                                                                           \
    const unsigned short* rp = kvl + (size_t)(SRC) * 512;                     \
    uint2 ku = *(const uint2*)rp;                                             \
    uint2 vu = *(const uint2*)(rp + 256);                                     \
    float p = bflo(ku.x) * qv.x + bfhi(ku.x) * qv.y +                         \
              bflo(ku.y) * qv.z + bfhi(ku.y) * qv.w;                          \
    p += __shfl_xor(p, 1);                                                    \
    p += __shfl_xor(p, 2);                                                    \
    p += __shfl_xor(p, 4);                                                    \
    p += __shfl_xor(p, 8);                                                    \
    float e0 = __expf(fminf(fmaxf(p * 0.125f, -5.f), 5.f));                   \
    a0 = fmaf(e0, bflo(vu.x), a0);                                            \
    a1 = fmaf(e0, bfhi(vu.x), a1);                                            \
    a2 = fmaf(e0, bflo(vu.y), a2);                                            \
    a3 = fmaf(e0, bfhi(vu.y), a3);                                            \
    z += e0;                                                                  \
  }

  for (int base = beg; base < end; base += 64) {
    int idx = base + lane;
    int eid = (idx < end) ? csr_src[idx] : 0;
    int bs = min(64, end - base);
    int j = 0;
    for (; j + 4 <= bs; j += 4) {
      int s0 = __builtin_amdgcn_readlane(eid, j);
      int s1 = __builtin_amdgcn_readlane(eid, j + 1);
      int s2 = __builtin_amdgcn_readlane(eid, j + 2);
      int s3 = __builtin_amdgcn_readlane(eid, j + 3);
      EDGE_BODY(s0); EDGE_BODY(s1); EDGE_BODY(s2); EDGE_BODY(s3);
    }
    for (; j < bs; j++) {
      int s0 = __builtin_amdgcn_readlane(eid, j);
      EDGE_BODY(s0);
    }
  }
#undef EDGE_BODY

  float invz = 1.f / z;
  float4 r;
  r.x = a0 * invz; r.y = a1 * invz; r.z = a2 * invz; r.w = a3 * invz;
  *(float4*)(att + (size_t)n * 256 + lane * 4) = r;
}

// ---------------- BN stats ----------------
__global__ void k_bnstats(const float* __restrict__ o, float* __restrict__ bnsum,
                          float* __restrict__ bnsq) {
  int d = threadIdx.x;
  float s = 0.f, sq = 0.f;
  for (int r = blockIdx.x; r < N_NODES; r += gridDim.x) {
    float val = o[(size_t)r * 256 + d];
    s += val;
    sq = fmaf(val, val, sq);
  }
  atomicAdd(&bnsum[d], s);
  atomicAdd(&bnsq[d], sq);
}

__global__ void k_bnfinal(const float* __restrict__ bnsum, const float* __restrict__ bnsq,
                          const float* __restrict__ gamma, const float* __restrict__ beta,
                          float* __restrict__ scale, float* __restrict__ shift) {
  int d = threadIdx.x;
  float mean = bnsum[d] * (1.f / N_NODES);
  float var = bnsq[d] * (1.f / N_NODES) - mean * mean;
  float istd = rsqrtf(var + 1e-5f);
  float sc = gamma[d] * istd;
  scale[d] = sc;
  shift[d] = beta[d] - mean * sc;
}

// ---------------- fused BN-apply + SE block ----------------
__global__ __launch_bounds__(256) void k_se(
    const float* __restrict__ o, const float* __restrict__ scale,
    const float* __restrict__ shift, const float* __restrict__ W1,
    const float* __restrict__ b1, const float* __restrict__ W2,
    const float* __restrict__ b2, const float* __restrict__ v,
    float* __restrict__ out) {
  __shared__ float xl[4][256];
  __shared__ float hl[4][64];
  int lane = threadIdx.x & 63, wid = threadIdx.x >> 6;
  int n = blockIdx.x * 4 + wid;
  int d0 = lane * 4;
  float4 ov = *(const float4*)(o + (size_t)n * 256 + d0);
  float4 xv;
  xv.x = relu6f(fmaf(ov.x, scale[d0 + 0], shift[d0 + 0]));
  xv.y = relu6f(fmaf(ov.y, scale[d0 + 1], shift[d0 + 1]));
  xv.z = relu6f(fmaf(ov.z, scale[d0 + 2], shift[d0 + 2]));
  xv.w = relu6f(fmaf(ov.w, scale[d0 + 3], shift[d0 + 3]));
  *(float4*)&xl[wid][d0] = xv;
  __syncthreads();
  float acc = b1[lane];
#pragma unroll 8
  for (int d = 0; d < 256; d++) acc = fmaf(xl[wid][d], W1[d * 64 + lane], acc);
  hl[wid][lane] = relu6f(acc);
  __syncthreads();
#pragma unroll
  for (int m = 0; m < 4; m++) {
    int d = m * 64 + lane;
    float se = b2[d];
#pragma unroll 8
    for (int h = 0; h < 64; h++) se = fmaf(hl[wid][h], W2[h * 256 + d], se);
    float hs = se * relu6f(se + 3.f) * (1.f / 6.f);
    size_t idx = (size_t)n * 256 + d;
    out[idx] = fmaf(hs, xl[wid][d], v[idx]);
  }
}

extern "C" void kernel_launch(void* const* d_in, const int* in_sizes, int n_in,
                              void* d_out, int out_size, void* d_ws, size_t ws_size,
                              hipStream_t stream) {
  const float* v     = (const float*)d_in[0];
  const float* WQ    = (const float*)d_in[1];
  const float* bQ    = (const float*)d_in[2];
  const float* WK    = (const float*)d_in[3];
  const float* bK    = (const float*)d_in[4];
  const float* WV    = (const float*)d_in[5];
  const float* bV    = (const float*)d_in[6];
  const float* Wo    = (const float*)d_in[7];
  const float* bo    = (const float*)d_in[8];
  const float* W1    = (const float*)d_in[9];
  const float* b1    = (const float*)d_in[10];
  const float* W2    = (const float*)d_in[11];
  const float* b2    = (const float*)d_in[12];
  const float* gamma = (const float*)d_in[13];
  const float* beta  = (const float*)d_in[14];
  const int* srcI    = (const int*)d_in[15];
  const int* dstI    = (const int*)d_in[16];
  float* out = (float*)d_out;

  char* w = (char*)d_ws;
  size_t off = 0;
  auto take = [&](size_t bytes) {
    size_t o = off;
    off += (bytes + 255) & ~(size_t)255;
    return o;
  };
  // zeroed region (single memset): inc | outc | bnsum | bnsq | Zd
  int* inc      = (int*)(w + take(N_NODES * 4));
  int* outc     = (int*)(w + take(N_NODES * 4));
  float* bnsum  = (float*)(w + take(256 * 4));
  float* bnsq   = (float*)(w + take(256 * 4));
  double* Zd    = (double*)(w + take(8));
  size_t zero_span = off;
  float* logzf  = (float*)(w + take(4));
  float* q      = (float*)(w + take(ND * 4));
  unsigned short* kvb = (unsigned short*)(w + take((size_t)N_NODES * 512 * 2));
  float* scale  = (float*)(w + take(256 * 4));
  float* shift  = (float*)(w + take(256 * 4));
  int* rowptr   = (int*)(w + take((N_NODES + 1) * 4));
  int* nextp    = (int*)(w + take(N_NODES * 4));
  int* csr_src  = (int*)(w + take((size_t)N_EDGES * 4));
  short* Wt_hi  = (short*)(w + take((size_t)4 * 65536 * 2));
  short* Wt_lo  = (short*)(w + take((size_t)4 * 65536 * 2));

  float* att = q;              // reuse: each edgeagg wave reads only its own q row first
  float* o   = (float*)kvb;    // reuse: kv dead after edgeagg (10.24 MB each)

  hipMemsetAsync(w, 0, zero_span, stream);

  k_wsplit<<<dim3(16, 4), dim3(256), 0, stream>>>(WQ, WK, WV, Wo, Wt_hi, Wt_lo);
  k_deg<<<dim3((N_EDGES + 255) / 256), dim3(256), 0, stream>>>(srcI, dstI, outc, inc);
  k_expsum<<<dim3((N_NODES + 255) / 256), dim3(256), 0, stream>>>(inc, outc, Zd);
  k_scan<<<dim3(1), dim3(1024), 0, stream>>>(inc, rowptr, nextp, Zd, logzf);
  k_fill<<<dim3((N_EDGES + 255) / 256), dim3(256), 0, stream>>>(srcI, dstI, nextp, csr_src);

  // q (fp32), k/vv (bf16, interleaved kv) = (v*center) @ {WQ,WK,WV} + b
  k_gemm_mfma<1, 1><<<dim3(157, 2, 3), dim3(256), 0, stream>>>(
      v, Wt_hi, Wt_lo, bQ, bK, bV, inc, outc, logzf, q, kvb, nullptr, N_NODES);

  k_edgeagg<<<dim3(N_NODES / 4), dim3(256), 0, stream>>>(rowptr, csr_src, q, kvb, att);

  // o = att @ Wo + bo
  k_gemm_mfma<0, 0><<<dim3(157, 2, 1), dim3(256), 0, stream>>>(
      att, Wt_hi + (size_t)3 * 65536, Wt_lo + (size_t)3 * 65536,
      bo, bo, bo, nullptr, nullptr, nullptr, nullptr, nullptr, o, N_NODES);

  k_bnstats<<<dim3(240), dim3(256), 0, stream>>>(o, bnsum, bnsq);
  k_bnfinal<<<dim3(1), dim3(256), 0, stream>>>(bnsum, bnsq, gamma, beta, scale, shift);

  k_se<<<dim3(N_NODES / 4), dim3(256), 0, stream>>>(o, scale, shift, W1, b1, W2, b2, v, out);
}

// Round 7
// 298.896 us; speedup vs baseline: 1.8752x; 1.0636x over previous
//
#include <hip/hip_runtime.h>
#include <math.h>

#define N_NODES 10000
#define N_EDGES 320000
#define DIM 256
#define ND ((size_t)N_NODES * DIM)

typedef float f32x4 __attribute__((ext_vector_type(4)));
typedef short s16x8 __attribute__((ext_vector_type(8)));

__device__ __forceinline__ float relu6f(float x) { return fminf(fmaxf(x, 0.f), 6.f); }

__device__ __forceinline__ short f2bf(float x) {
  unsigned u = __builtin_bit_cast(unsigned, x);
  unsigned r = (u + 0x7fffu + ((u >> 16) & 1u)) >> 16;
  return (short)r;
}
__device__ __forceinline__ float bf2f(short b) {
  unsigned u = ((unsigned)(unsigned short)b) << 16;
  return __builtin_bit_cast(float, u);
}
__device__ __forceinline__ float bflo(unsigned u) {
  return __builtin_bit_cast(float, u << 16);
}
__device__ __forceinline__ float bfhi(unsigned u) {
  return __builtin_bit_cast(float, u & 0xffff0000u);
}

// ---------------- degree histograms ----------------
__global__ void k_deg(const int* __restrict__ src, const int* __restrict__ dst,
                      int* __restrict__ outc, int* __restrict__ inc) {
  int e = blockIdx.x * 256 + threadIdx.x;
  if (e < N_EDGES) {
    atomicAdd(&outc[src[e]], 1);
    atomicAdd(&inc[dst[e]], 1);
  }
}

// ---------------- sum of exp(deg) in double ----------------
__global__ void k_expsum(const int* __restrict__ inc, const int* __restrict__ outc,
                         double* __restrict__ Zd) {
  int i = blockIdx.x * 256 + threadIdx.x;
  int lane = threadIdx.x & 63;
  double e = 0.0;
  if (i < N_NODES) e = exp((double)(inc[i] + outc[i]));
#pragma unroll
  for (int off = 1; off < 64; off <<= 1) e += __shfl_xor(e, off);
  if (lane == 0) atomicAdd(Zd, e);
}

// ---------------- W transpose + bf16 hi/lo split (256x256 weights) ----------------
__global__ __launch_bounds__(256) void k_wsplit(
    const float* __restrict__ Wa, const float* __restrict__ Wb,
    const float* __restrict__ Wc, const float* __restrict__ Wd,
    short* __restrict__ Whi, short* __restrict__ Wlo) {
  const float* W = (blockIdx.y == 0) ? Wa : (blockIdx.y == 1) ? Wb
                   : (blockIdx.y == 2) ? Wc : Wd;
  short* hi = Whi + (size_t)blockIdx.y * 65536;
  short* lo = Wlo + (size_t)blockIdx.y * 65536;
  __shared__ float tile[64][65];
  int t = threadIdx.x;
  int tk = (blockIdx.x >> 2) * 64, tn = (blockIdx.x & 3) * 64;
  int r = t >> 4, c4 = (t & 15) * 4;
#pragma unroll
  for (int p = 0; p < 4; p++) {
    float4 v4 = *(const float4*)(W + (size_t)(tk + p * 16 + r) * 256 + tn + c4);
    tile[p * 16 + r][c4 + 0] = v4.x;
    tile[p * 16 + r][c4 + 1] = v4.y;
    tile[p * 16 + r][c4 + 2] = v4.z;
    tile[p * 16 + r][c4 + 3] = v4.w;
  }
  __syncthreads();
  int nl = t >> 2, q = t & 3;
  s16x8 h0, h1, l0, l1;
#pragma unroll
  for (int j = 0; j < 8; j++) {
    float x = tile[q * 16 + j][nl];
    short hb = f2bf(x);
    h0[j] = hb; l0[j] = f2bf(x - bf2f(hb));
  }
#pragma unroll
  for (int j = 0; j < 8; j++) {
    float x = tile[q * 16 + 8 + j][nl];
    short hb = f2bf(x);
    h1[j] = hb; l1[j] = f2bf(x - bf2f(hb));
  }
  size_t base = (size_t)(tn + nl) * 256 + tk + q * 16;
  *(s16x8*)(hi + base) = h0;
  *(s16x8*)(hi + base + 8) = h1;
  *(s16x8*)(lo + base) = l0;
  *(s16x8*)(lo + base + 8) = l1;
}

// ---------------- generic W [K][N] -> Wt_hi/lo [N][K] bf16 split ----------------
// grid: (K/64, N/64)
__global__ __launch_bounds__(256) void k_wsplit_t(
    const float* __restrict__ W, short* __restrict__ hi, short* __restrict__ lo,
    int K, int N) {
  __shared__ float tile[64][65];
  int t = threadIdx.x;
  int tk = blockIdx.x * 64, tn = blockIdx.y * 64;
  int r = t >> 4, c4 = (t & 15) * 4;
#pragma unroll
  for (int p = 0; p < 4; p++) {
    float4 v4 = *(const float4*)(W + (size_t)(tk + p * 16 + r) * N + tn + c4);
    tile[p * 16 + r][c4 + 0] = v4.x;
    tile[p * 16 + r][c4 + 1] = v4.y;
    tile[p * 16 + r][c4 + 2] = v4.z;
    tile[p * 16 + r][c4 + 3] = v4.w;
  }
  __syncthreads();
  int nl = t >> 2, q = t & 3;
  s16x8 h0, h1, l0, l1;
#pragma unroll
  for (int j = 0; j < 8; j++) {
    float x = tile[q * 16 + j][nl];
    short hb = f2bf(x);
    h0[j] = hb; l0[j] = f2bf(x - bf2f(hb));
  }
#pragma unroll
  for (int j = 0; j < 8; j++) {
    float x = tile[q * 16 + 8 + j][nl];
    short hb = f2bf(x);
    h1[j] = hb; l1[j] = f2bf(x - bf2f(hb));
  }
  size_t base = (size_t)(tn + nl) * K + tk + q * 16;
  *(s16x8*)(hi + base) = h0;
  *(s16x8*)(hi + base + 8) = h1;
  *(s16x8*)(lo + base) = l0;
  *(s16x8*)(lo + base + 8) = l1;
}

// ---------------- bf16-split MFMA GEMM ----------------
// KVMODE=1: z=0 -> Q fp32 [N][256]; z=1 -> KV bf16 cols 0..255; z=2 -> KV bf16 cols 256..511
// KVMODE=0: z=0 -> Cbase fp32
template <int MULC, int KVMODE>
__global__ __launch_bounds__(256) void k_gemm_mfma(
    const float* __restrict__ A, const short* __restrict__ Whi,
    const short* __restrict__ Wlo, const float* __restrict__ b0,
    const float* __restrict__ b1, const float* __restrict__ b2,
    const int* __restrict__ inc, const int* __restrict__ outc,
    const float* __restrict__ logzf, float* __restrict__ Qout,
    unsigned short* __restrict__ KVout, float* __restrict__ Cbase, int M) {
  const float* bias = (blockIdx.z == 0) ? b0 : (blockIdx.z == 1) ? b1 : b2;
  const short* whi = Whi + (size_t)blockIdx.z * 65536;
  const short* wlo = Wlo + (size_t)blockIdx.z * 65536;

  __shared__ __align__(16) short Ah[64][40];
  __shared__ __align__(16) short Al[64][40];
  __shared__ __align__(16) short Bh[128][40];
  __shared__ __align__(16) short Bl[128][40];

  int tid = threadIdx.x;
  int lane = tid & 63, wid = tid >> 6;
  int wm = wid >> 1, wn = wid & 1;
  int m0 = blockIdx.x * 64;
  int n0g = blockIdx.y * 128;

  f32x4 acc[2][4];
#pragma unroll
  for (int i = 0; i < 2; i++)
#pragma unroll
    for (int j = 0; j < 4; j++) acc[i][j] = (f32x4){0.f, 0.f, 0.f, 0.f};

  int sa_row = tid >> 2, sa_seg = tid & 3;
  int sb_row = tid >> 1, sb_seg = tid & 1;
  float cmul = 1.f;
  if (MULC) {
    int m = m0 + sa_row;
    cmul = (m < M) ? __expf((float)(inc[m] + outc[m]) - logzf[0]) : 0.f;
  }

  for (int k0 = 0; k0 < 256; k0 += 32) {
    __syncthreads();
    {
      int m = m0 + sa_row;
      float4 x0 = make_float4(0.f, 0.f, 0.f, 0.f), x1 = x0;
      if (m < M) {
        const float* ap = A + (size_t)m * 256 + k0 + sa_seg * 8;
        x0 = *(const float4*)ap;
        x1 = *(const float4*)(ap + 4);
        if (MULC) {
          x0.x *= cmul; x0.y *= cmul; x0.z *= cmul; x0.w *= cmul;
          x1.x *= cmul; x1.y *= cmul; x1.z *= cmul; x1.w *= cmul;
        }
      }
      s16x8 h, l;
      float xs[8] = {x0.x, x0.y, x0.z, x0.w, x1.x, x1.y, x1.z, x1.w};
#pragma unroll
      for (int j = 0; j < 8; j++) {
        short hb = f2bf(xs[j]);
        h[j] = hb; l[j] = f2bf(xs[j] - bf2f(hb));
      }
      *(s16x8*)&Ah[sa_row][sa_seg * 8] = h;
      *(s16x8*)&Al[sa_row][sa_seg * 8] = l;
    }
    {
      size_t gb = (size_t)(n0g + sb_row) * 256 + k0 + sb_seg * 16;
      *(s16x8*)&Bh[sb_row][sb_seg * 16] = *(const s16x8*)(whi + gb);
      *(s16x8*)&Bh[sb_row][sb_seg * 16 + 8] = *(const s16x8*)(whi + gb + 8);
      *(s16x8*)&Bl[sb_row][sb_seg * 16] = *(const s16x8*)(wlo + gb);
      *(s16x8*)&Bl[sb_row][sb_seg * 16 + 8] = *(const s16x8*)(wlo + gb + 8);
    }
    __syncthreads();
    int arow0 = wm * 32 + (lane & 15);
    int kc = (lane >> 4) * 8;
    s16x8 ah[2], al[2], bh[4], bl[4];
#pragma unroll
    for (int mf = 0; mf < 2; mf++) {
      ah[mf] = *(const s16x8*)&Ah[arow0 + mf * 16][kc];
      al[mf] = *(const s16x8*)&Al[arow0 + mf * 16][kc];
    }
    int brow0 = wn * 64 + (lane & 15);
#pragma unroll
    for (int nf = 0; nf < 4; nf++) {
      bh[nf] = *(const s16x8*)&Bh[brow0 + nf * 16][kc];
      bl[nf] = *(const s16x8*)&Bl[brow0 + nf * 16][kc];
    }
#pragma unroll
    for (int mf = 0; mf < 2; mf++)
#pragma unroll
      for (int nf = 0; nf < 4; nf++) {
        acc[mf][nf] = __builtin_amdgcn_mfma_f32_16x16x32_bf16(ah[mf], bh[nf], acc[mf][nf], 0, 0, 0);
        acc[mf][nf] = __builtin_amdgcn_mfma_f32_16x16x32_bf16(al[mf], bh[nf], acc[mf][nf], 0, 0, 0);
        acc[mf][nf] = __builtin_amdgcn_mfma_f32_16x16x32_bf16(ah[mf], bl[nf], acc[mf][nf], 0, 0, 0);
      }
  }

  int colq = lane & 15, rowq = (lane >> 4) * 4;
  bool isq = (KVMODE == 0) || (blockIdx.z == 0);
  int kvoff = (blockIdx.z == 1) ? 0 : 256;
#pragma unroll
  for (int mf = 0; mf < 2; mf++) {
#pragma unroll
    for (int nf = 0; nf < 4; nf++) {
      int n = wn * 64 + nf * 16 + colq;
      float bv = bias[n0g + n];
#pragma unroll
      for (int j = 0; j < 4; j++) {
        int m = m0 + wm * 32 + mf * 16 + rowq + j;
        if (m >= M) continue;
        float val = acc[mf][nf][j] + bv;
        if (isq) {
          float* C = (KVMODE == 1) ? Qout : Cbase;
          C[(size_t)m * 256 + n0g + n] = val;
        } else {
          KVout[(size_t)m * 512 + kvoff + n0g + n] = (unsigned short)f2bf(val);
        }
      }
    }
  }
}

// ---------------- exclusive scan + logZ ----------------
__global__ void k_scan(const int* __restrict__ cnt, int* __restrict__ rowptr,
                       int* __restrict__ nextp, const double* __restrict__ Zd,
                       float* __restrict__ logzf) {
  __shared__ int wsum[16];
  __shared__ int carry_s;
  int tid = threadIdx.x, lane = tid & 63, wid = tid >> 6;
  if (tid == 0) {
    carry_s = 0;
    logzf[0] = (float)log(Zd[0]);
  }
  __syncthreads();
  for (int base = 0; base < N_NODES; base += 1024) {
    int i = base + tid;
    int v = (i < N_NODES) ? cnt[i] : 0;
    int x = v;
#pragma unroll
    for (int off = 1; off < 64; off <<= 1) {
      int t = __shfl_up(x, off);
      if (lane >= off) x += t;
    }
    if (lane == 63) wsum[wid] = x;
    __syncthreads();
    if (wid == 0 && lane < 16) {
      int wv = wsum[lane];
#pragma unroll
      for (int off = 1; off < 16; off <<= 1) {
        int t = __shfl_up(wv, off);
        if (lane >= off) wv += t;
      }
      wsum[lane] = wv;
    }
    __syncthreads();
    int carry = carry_s;
    int wadd = (wid > 0) ? wsum[wid - 1] : 0;
    int excl = carry + wadd + x - v;
    if (i < N_NODES) {
      rowptr[i] = excl;
      nextp[i] = excl;
    }
    __syncthreads();
    if (tid == 1023) carry_s = excl + v;
    __syncthreads();
  }
  if (tid == 0) rowptr[N_NODES] = carry_s;
}

// ---------------- CSR fill ----------------
__global__ void k_fill(const int* __restrict__ src, const int* __restrict__ dst,
                       int* __restrict__ nextp, int* __restrict__ csr_src) {
  int e = blockIdx.x * 256 + threadIdx.x;
  if (e < N_EDGES) {
    int pos = atomicAdd(&nextp[dst[e]], 1);
    csr_src[pos] = src[e];
  }
}

// ---------------- fused edge-score + aggregation (bf16 kv, wave per node) ----------------
__global__ __launch_bounds__(256) void k_edgeagg(
    const int* __restrict__ rowptr, const int* __restrict__ csr_src,
    const float* __restrict__ q, const unsigned short* __restrict__ kv,
    float* __restrict__ att) {
  int lane = threadIdx.x & 63, wid = threadIdx.x >> 6;
  int n = blockIdx.x * 4 + wid;
  int beg = rowptr[n], end = rowptr[n + 1];
  float4 qv = *(const float4*)(q + (size_t)n * 256 + lane * 4);
  const unsigned short* kvl = kv + lane * 4;
  float a0 = 0.f, a1 = 0.f, a2 = 0.f, a3 = 0.f, z = 0.f;

#define EDGE_BODY(SRC)                                                        \
  {                                                                           \
    const unsigned short* rp = kvl + (size_t)(SRC) * 512;                     \
    uint2 ku = *(const uint2*)rp;                                             \
    uint2 vu = *(const uint2*)(rp + 256);                                     \
    float p = bflo(ku.x) * qv.x + bfhi(ku.x) * qv.y +                         \
              bflo(ku.y) * qv.z + bfhi(ku.y) * qv.w;                          \
    p += __shfl_xor(p, 1);                                                    \
    p += __shfl_xor(p, 2);                                                    \
    p += __shfl_xor(p, 4);                                                    \
    p += __shfl_xor(p, 8);                                                    \
    float e0 = __expf(fminf(fmaxf(p * 0.125f, -5.f), 5.f));                   \
    a0 = fmaf(e0, bflo(vu.x), a0);                                            \
    a1 = fmaf(e0, bfhi(vu.x), a1);                                            \
    a2 = fmaf(e0, bflo(vu.y), a2);                                            \
    a3 = fmaf(e0, bfhi(vu.y), a3);                                            \
    z += e0;                                                                  \
  }

  for (int base = beg; base < end; base += 64) {
    int idx = base + lane;
    int eid = (idx < end) ? csr_src[idx] : 0;
    int bs = min(64, end - base);
    int j = 0;
    for (; j + 4 <= bs; j += 4) {
      int s0 = __builtin_amdgcn_readlane(eid, j);
      int s1 = __builtin_amdgcn_readlane(eid, j + 1);
      int s2 = __builtin_amdgcn_readlane(eid, j + 2);
      int s3 = __builtin_amdgcn_readlane(eid, j + 3);
      EDGE_BODY(s0); EDGE_BODY(s1); EDGE_BODY(s2); EDGE_BODY(s3);
    }
    for (; j < bs; j++) {
      int s0 = __builtin_amdgcn_readlane(eid, j);
      EDGE_BODY(s0);
    }
  }
#undef EDGE_BODY

  float invz = 1.f / z;
  float4 r;
  r.x = a0 * invz; r.y = a1 * invz; r.z = a2 * invz; r.w = a3 * invz;
  *(float4*)(att + (size_t)n * 256 + lane * 4) = r;
}

// ---------------- BN stats ----------------
__global__ void k_bnstats(const float* __restrict__ o, float* __restrict__ bnsum,
                          float* __restrict__ bnsq) {
  int d = threadIdx.x;
  float s = 0.f, sq = 0.f;
  for (int r = blockIdx.x; r < N_NODES; r += gridDim.x) {
    float val = o[(size_t)r * 256 + d];
    s += val;
    sq = fmaf(val, val, sq);
  }
  atomicAdd(&bnsum[d], s);
  atomicAdd(&bnsq[d], sq);
}

__global__ void k_bnfinal(const float* __restrict__ bnsum, const float* __restrict__ bnsq,
                          const float* __restrict__ gamma, const float* __restrict__ beta,
                          float* __restrict__ scale, float* __restrict__ shift) {
  int d = threadIdx.x;
  float mean = bnsum[d] * (1.f / N_NODES);
  float var = bnsq[d] * (1.f / N_NODES) - mean * mean;
  float istd = rsqrtf(var + 1e-5f);
  float sc = gamma[d] * istd;
  scale[d] = sc;
  shift[d] = beta[d] - mean * sc;
}

// ---------------- fused BN-apply + SE block, MFMA version ----------------
// block = 64 nodes, 4 waves; wave w owns rows 16w..16w+15.
// phase0: x = relu6(o*scale+shift) -> bf16 hi/lo in LDS; v staged in LDS.
// phase1: hidden = relu6(x @ W1 + b1) via 3-MFMA bf16 split; split to LDS.
// phase2: se = hidden @ W2 + b2; out = hswish(se)*x + v.
__global__ __launch_bounds__(256) void k_se2(
    const float* __restrict__ o, const float* __restrict__ scale,
    const float* __restrict__ shift,
    const short* __restrict__ W1h, const short* __restrict__ W1l,
    const float* __restrict__ b1,
    const short* __restrict__ W2h, const short* __restrict__ W2l,
    const float* __restrict__ b2,
    const float* __restrict__ vin, float* __restrict__ out) {
  __shared__ __align__(16) short xh[64][264];
  __shared__ __align__(16) short xl[64][264];
  __shared__ __align__(16) short hh[64][72];
  __shared__ __align__(16) short hl[64][72];
  __shared__ float vt[64][256];

  int t = threadIdx.x;
  int lane = t & 63, w = t >> 6;
  int m0 = blockIdx.x * 64;

  // ---- phase 0 ----
  {
    int r = t >> 2;
    int cb = (t & 3) * 4;
    int gr = m0 + r;
    bool rok = gr < N_NODES;
#pragma unroll
    for (int p = 0; p < 16; p++) {
      int c = cb + p * 16;
      float4 ov = make_float4(0.f, 0.f, 0.f, 0.f), vv = ov;
      if (rok) {
        ov = *(const float4*)(o + (size_t)gr * 256 + c);
        vv = *(const float4*)(vin + (size_t)gr * 256 + c);
      }
      float xs[4];
      xs[0] = relu6f(fmaf(ov.x, scale[c + 0], shift[c + 0]));
      xs[1] = relu6f(fmaf(ov.y, scale[c + 1], shift[c + 1]));
      xs[2] = relu6f(fmaf(ov.z, scale[c + 2], shift[c + 2]));
      xs[3] = relu6f(fmaf(ov.w, scale[c + 3], shift[c + 3]));
#pragma unroll
      for (int j = 0; j < 4; j++) {
        short hb = f2bf(xs[j]);
        xh[r][c + j] = hb;
        xl[r][c + j] = f2bf(xs[j] - bf2f(hb));
      }
      *(float4*)&vt[r][c] = vv;
    }
  }
  __syncthreads();

  int fr = lane & 15, fq = lane >> 4;
  int kc = fq * 8;
  int arow = w * 16 + fr;

  // ---- phase 1: hidden = relu6(x @ W1 + b1) ----
  f32x4 acc1[4];
#pragma unroll
  for (int nf = 0; nf < 4; nf++) acc1[nf] = (f32x4){0.f, 0.f, 0.f, 0.f};
#pragma unroll
  for (int ks = 0; ks < 8; ks++) {
    s16x8 ah = *(const s16x8*)&xh[arow][ks * 32 + kc];
    s16x8 al = *(const s16x8*)&xl[arow][ks * 32 + kc];
#pragma unroll
    for (int nf = 0; nf < 4; nf++) {
      size_t bo_ = (size_t)(nf * 16 + fr) * 256 + ks * 32 + kc;
      s16x8 bh = *(const s16x8*)(W1h + bo_);
      s16x8 bl = *(const s16x8*)(W1l + bo_);
      acc1[nf] = __builtin_amdgcn_mfma_f32_16x16x32_bf16(ah, bh, acc1[nf], 0, 0, 0);
      acc1[nf] = __builtin_amdgcn_mfma_f32_16x16x32_bf16(al, bh, acc1[nf], 0, 0, 0);
      acc1[nf] = __builtin_amdgcn_mfma_f32_16x16x32_bf16(ah, bl, acc1[nf], 0, 0, 0);
    }
  }
#pragma unroll
  for (int nf = 0; nf < 4; nf++) {
    int n = nf * 16 + fr;
    float bv = b1[n];
#pragma unroll
    for (int j = 0; j < 4; j++) {
      int row = w * 16 + fq * 4 + j;
      float hv = relu6f(acc1[nf][j] + bv);
      short hb = f2bf(hv);
      hh[row][n] = hb;
      hl[row][n] = f2bf(hv - bf2f(hb));
    }
  }
  __syncthreads();

  // ---- phase 2: se = hidden @ W2 + b2; out = hswish(se)*x + v ----
  f32x4 acc2[16];
#pragma unroll
  for (int nf = 0; nf < 16; nf++) acc2[nf] = (f32x4){0.f, 0.f, 0.f, 0.f};
#pragma unroll
  for (int ks = 0; ks < 2; ks++) {
    s16x8 ah = *(const s16x8*)&hh[arow][ks * 32 + kc];
    s16x8 al = *(const s16x8*)&hl[arow][ks * 32 + kc];
#pragma unroll
    for (int nf = 0; nf < 16; nf++) {
      size_t bo_ = (size_t)(nf * 16 + fr) * 64 + ks * 32 + kc;
      s16x8 bh = *(const s16x8*)(W2h + bo_);
      s16x8 bl = *(const s16x8*)(W2l + bo_);
      acc2[nf] = __builtin_amdgcn_mfma_f32_16x16x32_bf16(ah, bh, acc2[nf], 0, 0, 0);
      acc2[nf] = __builtin_amdgcn_mfma_f32_16x16x32_bf16(al, bh, acc2[nf], 0, 0, 0);
      acc2[nf] = __builtin_amdgcn_mfma_f32_16x16x32_bf16(ah, bl, acc2[nf], 0, 0, 0);
    }
  }
#pragma unroll
  for (int nf = 0; nf < 16; nf++) {
    int col = nf * 16 + fr;
    float bv = b2[col];
#pragma unroll
    for (int j = 0; j < 4; j++) {
      int row = w * 16 + fq * 4 + j;
      int grow = m0 + row;
      if (grow < N_NODES) {
        float se = acc2[nf][j] + bv;
        float hs = se * relu6f(se + 3.f) * (1.f / 6.f);
        float xr = bf2f(xh[row][col]) + bf2f(xl[row][col]);
        out[(size_t)grow * 256 + col] = fmaf(hs, xr, vt[row][col]);
      }
    }
  }
}

extern "C" void kernel_launch(void* const* d_in, const int* in_sizes, int n_in,
                              void* d_out, int out_size, void* d_ws, size_t ws_size,
                              hipStream_t stream) {
  const float* v     = (const float*)d_in[0];
  const float* WQ    = (const float*)d_in[1];
  const float* bQ    = (const float*)d_in[2];
  const float* WK    = (const float*)d_in[3];
  const float* bK    = (const float*)d_in[4];
  const float* WV    = (const float*)d_in[5];
  const float* bV    = (const float*)d_in[6];
  const float* Wo    = (const float*)d_in[7];
  const float* bo    = (const float*)d_in[8];
  const float* W1    = (const float*)d_in[9];
  const float* b1    = (const float*)d_in[10];
  const float* W2    = (const float*)d_in[11];
  const float* b2    = (const float*)d_in[12];
  const float* gamma = (const float*)d_in[13];
  const float* beta  = (const float*)d_in[14];
  const int* srcI    = (const int*)d_in[15];
  const int* dstI    = (const int*)d_in[16];
  float* out = (float*)d_out;

  char* w = (char*)d_ws;
  size_t off = 0;
  auto take = [&](size_t bytes) {
    size_t o = off;
    off += (bytes + 255) & ~(size_t)255;
    return o;
  };
  // zeroed region (single memset): inc | outc | bnsum | bnsq | Zd
  int* inc      = (int*)(w + take(N_NODES * 4));
  int* outc     = (int*)(w + take(N_NODES * 4));
  float* bnsum  = (float*)(w + take(256 * 4));
  float* bnsq   = (float*)(w + take(256 * 4));
  double* Zd    = (double*)(w + take(8));
  size_t zero_span = off;
  float* logzf  = (float*)(w + take(4));
  float* q      = (float*)(w + take(ND * 4));
  unsigned short* kvb = (unsigned short*)(w + take((size_t)N_NODES * 512 * 2));
  float* scale  = (float*)(w + take(256 * 4));
  float* shift  = (float*)(w + take(256 * 4));
  int* rowptr   = (int*)(w + take((N_NODES + 1) * 4));
  int* nextp    = (int*)(w + take(N_NODES * 4));
  int* csr_src  = (int*)(w + take((size_t)N_EDGES * 4));
  short* Wt_hi  = (short*)(w + take((size_t)4 * 65536 * 2));
  short* Wt_lo  = (short*)(w + take((size_t)4 * 65536 * 2));
  short* W1h    = (short*)(w + take((size_t)16384 * 2));
  short* W1l    = (short*)(w + take((size_t)16384 * 2));
  short* W2h    = (short*)(w + take((size_t)16384 * 2));
  short* W2l    = (short*)(w + take((size_t)16384 * 2));

  float* att = q;              // reuse: each edgeagg wave reads only its own q row first
  float* o   = (float*)kvb;    // reuse: kv dead after edgeagg (10.24 MB each)

  hipMemsetAsync(w, 0, zero_span, stream);

  k_wsplit<<<dim3(16, 4), dim3(256), 0, stream>>>(WQ, WK, WV, Wo, Wt_hi, Wt_lo);
  k_wsplit_t<<<dim3(4, 1), dim3(256), 0, stream>>>(W1, W1h, W1l, 256, 64);
  k_wsplit_t<<<dim3(1, 4), dim3(256), 0, stream>>>(W2, W2h, W2l, 64, 256);
  k_deg<<<dim3((N_EDGES + 255) / 256), dim3(256), 0, stream>>>(srcI, dstI, outc, inc);
  k_expsum<<<dim3((N_NODES + 255) / 256), dim3(256), 0, stream>>>(inc, outc, Zd);
  k_scan<<<dim3(1), dim3(1024), 0, stream>>>(inc, rowptr, nextp, Zd, logzf);
  k_fill<<<dim3((N_EDGES + 255) / 256), dim3(256), 0, stream>>>(srcI, dstI, nextp, csr_src);

  // q (fp32), k/vv (bf16, interleaved kv) = (v*center) @ {WQ,WK,WV} + b
  k_gemm_mfma<1, 1><<<dim3(157, 2, 3), dim3(256), 0, stream>>>(
      v, Wt_hi, Wt_lo, bQ, bK, bV, inc, outc, logzf, q, kvb, nullptr, N_NODES);

  k_edgeagg<<<dim3(N_NODES / 4), dim3(256), 0, stream>>>(rowptr, csr_src, q, kvb, att);

  // o = att @ Wo + bo
  k_gemm_mfma<0, 0><<<dim3(157, 2, 1), dim3(256), 0, stream>>>(
      att, Wt_hi + (size_t)3 * 65536, Wt_lo + (size_t)3 * 65536,
      bo, bo, bo, nullptr, nullptr, nullptr, nullptr, nullptr, o, N_NODES);

  k_bnstats<<<dim3(240), dim3(256), 0, stream>>>(o, bnsum, bnsq);
  k_bnfinal<<<dim3(1), dim3(256), 0, stream>>>(bnsum, bnsq, gamma, beta, scale, shift);

  k_se2<<<dim3((N_NODES + 63) / 64), dim3(256), 0, stream>>>(
      o, scale, shift, W1h, W1l, b1, W2h, W2l, b2, v, out);
}

// Round 11
// 293.366 us; speedup vs baseline: 1.9106x; 1.0189x over previous
//
#include <hip/hip_runtime.h>
#include <math.h>

#define N_NODES 10000
#define N_EDGES 320000
#define DIM 256
#define ND ((size_t)N_NODES * DIM)

typedef float f32x4 __attribute__((ext_vector_type(4)));
typedef short s16x8 __attribute__((ext_vector_type(8)));
typedef short s16x4 __attribute__((ext_vector_type(4)));

__device__ __forceinline__ float relu6f(float x) { return fminf(fmaxf(x, 0.f), 6.f); }

__device__ __forceinline__ short f2bf(float x) {
  unsigned u = __builtin_bit_cast(unsigned, x);
  unsigned r = (u + 0x7fffu + ((u >> 16) & 1u)) >> 16;
  return (short)r;
}
__device__ __forceinline__ float bf2f(short b) {
  unsigned u = ((unsigned)(unsigned short)b) << 16;
  return __builtin_bit_cast(float, u);
}
__device__ __forceinline__ float bflo(unsigned u) {
  return __builtin_bit_cast(float, u << 16);
}
__device__ __forceinline__ float bfhi(unsigned u) {
  return __builtin_bit_cast(float, u & 0xffff0000u);
}

// ---------------- degree histograms ----------------
__global__ void k_deg(const int* __restrict__ src, const int* __restrict__ dst,
                      int* __restrict__ outc, int* __restrict__ inc) {
  int e = blockIdx.x * 256 + threadIdx.x;
  if (e < N_EDGES) {
    atomicAdd(&outc[src[e]], 1);
    atomicAdd(&inc[dst[e]], 1);
  }
}

// ---------------- sum of exp(deg) in double ----------------
__global__ void k_expsum(const int* __restrict__ inc, const int* __restrict__ outc,
                         double* __restrict__ Zd) {
  int i = blockIdx.x * 256 + threadIdx.x;
  int lane = threadIdx.x & 63;
  double e = 0.0;
  if (i < N_NODES) e = exp((double)(inc[i] + outc[i]));
#pragma unroll
  for (int off = 1; off < 64; off <<= 1) e += __shfl_xor(e, off);
  if (lane == 0) atomicAdd(Zd, e);
}

// ---------------- W transpose + bf16 hi/lo split (256x256 weights) ----------------
__global__ __launch_bounds__(256) void k_wsplit(
    const float* __restrict__ Wa, const float* __restrict__ Wb,
    const float* __restrict__ Wc, const float* __restrict__ Wd,
    short* __restrict__ Whi, short* __restrict__ Wlo) {
  const float* W = (blockIdx.y == 0) ? Wa : (blockIdx.y == 1) ? Wb
                   : (blockIdx.y == 2) ? Wc : Wd;
  short* hi = Whi + (size_t)blockIdx.y * 65536;
  short* lo = Wlo + (size_t)blockIdx.y * 65536;
  __shared__ float tile[64][65];
  int t = threadIdx.x;
  int tk = (blockIdx.x >> 2) * 64, tn = (blockIdx.x & 3) * 64;
  int r = t >> 4, c4 = (t & 15) * 4;
#pragma unroll
  for (int p = 0; p < 4; p++) {
    float4 v4 = *(const float4*)(W + (size_t)(tk + p * 16 + r) * 256 + tn + c4);
    tile[p * 16 + r][c4 + 0] = v4.x;
    tile[p * 16 + r][c4 + 1] = v4.y;
    tile[p * 16 + r][c4 + 2] = v4.z;
    tile[p * 16 + r][c4 + 3] = v4.w;
  }
  __syncthreads();
  int nl = t >> 2, q = t & 3;
  s16x8 h0, h1, l0, l1;
#pragma unroll
  for (int j = 0; j < 8; j++) {
    float x = tile[q * 16 + j][nl];
    short hb = f2bf(x);
    h0[j] = hb; l0[j] = f2bf(x - bf2f(hb));
  }
#pragma unroll
  for (int j = 0; j < 8; j++) {
    float x = tile[q * 16 + 8 + j][nl];
    short hb = f2bf(x);
    h1[j] = hb; l1[j] = f2bf(x - bf2f(hb));
  }
  size_t base = (size_t)(tn + nl) * 256 + tk + q * 16;
  *(s16x8*)(hi + base) = h0;
  *(s16x8*)(hi + base + 8) = h1;
  *(s16x8*)(lo + base) = l0;
  *(s16x8*)(lo + base + 8) = l1;
}

// ---------------- generic W [K][N] -> Wt_hi/lo [N][K] bf16 split ----------------
__global__ __launch_bounds__(256) void k_wsplit_t(
    const float* __restrict__ W, short* __restrict__ hi, short* __restrict__ lo,
    int K, int N) {
  __shared__ float tile[64][65];
  int t = threadIdx.x;
  int tk = blockIdx.x * 64, tn = blockIdx.y * 64;
  int r = t >> 4, c4 = (t & 15) * 4;
#pragma unroll
  for (int p = 0; p < 4; p++) {
    float4 v4 = *(const float4*)(W + (size_t)(tk + p * 16 + r) * N + tn + c4);
    tile[p * 16 + r][c4 + 0] = v4.x;
    tile[p * 16 + r][c4 + 1] = v4.y;
    tile[p * 16 + r][c4 + 2] = v4.z;
    tile[p * 16 + r][c4 + 3] = v4.w;
  }
  __syncthreads();
  int nl = t >> 2, q = t & 3;
  s16x8 h0, h1, l0, l1;
#pragma unroll
  for (int j = 0; j < 8; j++) {
    float x = tile[q * 16 + j][nl];
    short hb = f2bf(x);
    h0[j] = hb; l0[j] = f2bf(x - bf2f(hb));
  }
#pragma unroll
  for (int j = 0; j < 8; j++) {
    float x = tile[q * 16 + 8 + j][nl];
    short hb = f2bf(x);
    h1[j] = hb; l1[j] = f2bf(x - bf2f(hb));
  }
  size_t base = (size_t)(tn + nl) * K + tk + q * 16;
  *(s16x8*)(hi + base) = h0;
  *(s16x8*)(hi + base + 8) = h1;
  *(s16x8*)(lo + base) = l0;
  *(s16x8*)(lo + base + 8) = l1;
}

// ---------------- A = (v .* center) -> global bf16 hi/lo, one pass ----------------
__global__ __launch_bounds__(256) void k_asplit(
    const float* __restrict__ v, const int* __restrict__ inc,
    const int* __restrict__ outc, const float* __restrict__ logzf,
    short* __restrict__ Ahg, short* __restrict__ Alg) {
  size_t idx = ((size_t)blockIdx.x * 256 + threadIdx.x) * 4;
  if (idx >= ND) return;
  int row = (int)(idx >> 8);
  float c = __expf((float)(inc[row] + outc[row]) - logzf[0]);
  float4 x = *(const float4*)(v + idx);
  float xs[4] = {x.x * c, x.y * c, x.z * c, x.w * c};
  s16x4 h, l;
#pragma unroll
  for (int j = 0; j < 4; j++) {
    short hb = f2bf(xs[j]);
    h[j] = hb;
    l[j] = f2bf(xs[j] - bf2f(hb));
  }
  *(s16x4*)(Ahg + idx) = h;
  *(s16x4*)(Alg + idx) = l;
}

// ---------------- bf16-split MFMA GEMM (A pre-split in global) ----------------
// KVMODE=1: z=0 -> Qout fp32; z=1 -> KV bf16 cols 0..255; z=2 -> KV cols 256..511
// KVMODE=0: z=0 -> Cbase fp32, + BN column sums via atomics
template <int KVMODE>
__global__ __launch_bounds__(256) void k_gemm_mfma(
    const short* __restrict__ Ahg, const short* __restrict__ Alg,
    const short* __restrict__ Whi, const short* __restrict__ Wlo,
    const float* __restrict__ b0, const float* __restrict__ b1,
    const float* __restrict__ b2, float* __restrict__ Qout,
    unsigned short* __restrict__ KVout, float* __restrict__ Cbase,
    float* __restrict__ bnsum, float* __restrict__ bnsq, int M) {
  const float* bias = (blockIdx.z == 0) ? b0 : (blockIdx.z == 1) ? b1 : b2;
  const short* whi = Whi + (size_t)blockIdx.z * 65536;
  const short* wlo = Wlo + (size_t)blockIdx.z * 65536;

  __shared__ __align__(16) short Ah[64][40];
  __shared__ __align__(16) short Al[64][40];
  __shared__ __align__(16) short Bh[128][40];
  __shared__ __align__(16) short Bl[128][40];

  int tid = threadIdx.x;
  int lane = tid & 63, wid = tid >> 6;
  int wm = wid >> 1, wn = wid & 1;
  int m0 = blockIdx.x * 64;
  int n0g = blockIdx.y * 128;

  f32x4 acc[2][4];
#pragma unroll
  for (int i = 0; i < 2; i++)
#pragma unroll
    for (int j = 0; j < 4; j++) acc[i][j] = (f32x4){0.f, 0.f, 0.f, 0.f};

  int sa_row = tid >> 2, sa_seg = tid & 3;
  int sb_row = tid >> 1, sb_seg = tid & 1;
  const s16x8 zero8 = {0, 0, 0, 0, 0, 0, 0, 0};

  for (int k0 = 0; k0 < 256; k0 += 32) {
    __syncthreads();
    {
      int m = m0 + sa_row;
      s16x8 h = zero8, l = zero8;
      if (m < M) {
        size_t ga = (size_t)m * 256 + k0 + sa_seg * 8;
        h = *(const s16x8*)(Ahg + ga);
        l = *(const s16x8*)(Alg + ga);
      }
      *(s16x8*)&Ah[sa_row][sa_seg * 8] = h;
      *(s16x8*)&Al[sa_row][sa_seg * 8] = l;
    }
    {
      size_t gb = (size_t)(n0g + sb_row) * 256 + k0 + sb_seg * 16;
      *(s16x8*)&Bh[sb_row][sb_seg * 16] = *(const s16x8*)(whi + gb);
      *(s16x8*)&Bh[sb_row][sb_seg * 16 + 8] = *(const s16x8*)(whi + gb + 8);
      *(s16x8*)&Bl[sb_row][sb_seg * 16] = *(const s16x8*)(wlo + gb);
      *(s16x8*)&Bl[sb_row][sb_seg * 16 + 8] = *(const s16x8*)(wlo + gb + 8);
    }
    __syncthreads();
    int arow0 = wm * 32 + (lane & 15);
    int kc = (lane >> 4) * 8;
    s16x8 ah[2], al[2], bh[4], bl[4];
#pragma unroll
    for (int mf = 0; mf < 2; mf++) {
      ah[mf] = *(const s16x8*)&Ah[arow0 + mf * 16][kc];
      al[mf] = *(const s16x8*)&Al[arow0 + mf * 16][kc];
    }
    int brow0 = wn * 64 + (lane & 15);
#pragma unroll
    for (int nf = 0; nf < 4; nf++) {
      bh[nf] = *(const s16x8*)&Bh[brow0 + nf * 16][kc];
      bl[nf] = *(const s16x8*)&Bl[brow0 + nf * 16][kc];
    }
#pragma unroll
    for (int mf = 0; mf < 2; mf++)
#pragma unroll
      for (int nf = 0; nf < 4; nf++) {
        acc[mf][nf] = __builtin_amdgcn_mfma_f32_16x16x32_bf16(ah[mf], bh[nf], acc[mf][nf], 0, 0, 0);
        acc[mf][nf] = __builtin_amdgcn_mfma_f32_16x16x32_bf16(al[mf], bh[nf], acc[mf][nf], 0, 0, 0);
        acc[mf][nf] = __builtin_amdgcn_mfma_f32_16x16x32_bf16(ah[mf], bl[nf], acc[mf][nf], 0, 0, 0);
      }
  }

  int colq = lane & 15, rowq = (lane >> 4) * 4;
  if (KVMODE == 1) {
    bool isq = (blockIdx.z == 0);
    int kvoff = (blockIdx.z == 1) ? 0 : 256;
#pragma unroll
    for (int mf = 0; mf < 2; mf++) {
#pragma unroll
      for (int nf = 0; nf < 4; nf++) {
        int n = wn * 64 + nf * 16 + colq;
        float bv = bias[n0g + n];
#pragma unroll
        for (int j = 0; j < 4; j++) {
          int m = m0 + wm * 32 + mf * 16 + rowq + j;
          if (m >= M) continue;
          float val = acc[mf][nf][j] + bv;
          if (isq) Qout[(size_t)m * 256 + n0g + n] = val;
          else KVout[(size_t)m * 512 + kvoff + n0g + n] = (unsigned short)f2bf(val);
        }
      }
    }
  } else {
    // C store + BN column partial sums
    float cs[4], cq[4];
#pragma unroll
    for (int nf = 0; nf < 4; nf++) { cs[nf] = 0.f; cq[nf] = 0.f; }
#pragma unroll
    for (int nf = 0; nf < 4; nf++) {
      int n = wn * 64 + nf * 16 + colq;
      float bv = bias[n0g + n];
#pragma unroll
      for (int mf = 0; mf < 2; mf++) {
#pragma unroll
        for (int j = 0; j < 4; j++) {
          int m = m0 + wm * 32 + mf * 16 + rowq + j;
          if (m >= M) continue;
          float val = acc[mf][nf][j] + bv;
          Cbase[(size_t)m * 256 + n0g + n] = val;
          cs[nf] += val;
          cq[nf] = fmaf(val, val, cq[nf]);
        }
      }
    }
    // reduce the 4 fq-lanes (lane, lane^16, lane^32, lane^48) per column
#pragma unroll
    for (int nf = 0; nf < 4; nf++) {
      float s = cs[nf], qq = cq[nf];
      s += __shfl_xor(s, 16); s += __shfl_xor(s, 32);
      qq += __shfl_xor(qq, 16); qq += __shfl_xor(qq, 32);
      if (lane < 16) {
        int n = n0g + wn * 64 + nf * 16 + lane;
        atomicAdd(&bnsum[n], s);
        atomicAdd(&bnsq[n], qq);
      }
    }
  }
}

// ---------------- exclusive scan + logZ ----------------
__global__ void k_scan(const int* __restrict__ cnt, int* __restrict__ rowptr,
                       int* __restrict__ nextp, const double* __restrict__ Zd,
                       float* __restrict__ logzf) {
  __shared__ int wsum[16];
  __shared__ int carry_s;
  int tid = threadIdx.x, lane = tid & 63, wid = tid >> 6;
  if (tid == 0) {
    carry_s = 0;
    logzf[0] = (float)log(Zd[0]);
  }
  __syncthreads();
  for (int base = 0; base < N_NODES; base += 1024) {
    int i = base + tid;
    int v = (i < N_NODES) ? cnt[i] : 0;
    int x = v;
#pragma unroll
    for (int off = 1; off < 64; off <<= 1) {
      int t = __shfl_up(x, off);
      if (lane >= off) x += t;
    }
    if (lane == 63) wsum[wid] = x;
    __syncthreads();
    if (wid == 0 && lane < 16) {
      int wv = wsum[lane];
#pragma unroll
      for (int off = 1; off < 16; off <<= 1) {
        int t = __shfl_up(wv, off);
        if (lane >= off) wv += t;
      }
      wsum[lane] = wv;
    }
    __syncthreads();
    int carry = carry_s;
    int wadd = (wid > 0) ? wsum[wid - 1] : 0;
    int excl = carry + wadd + x - v;
    if (i < N_NODES) {
      rowptr[i] = excl;
      nextp[i] = excl;
    }
    __syncthreads();
    if (tid == 1023) carry_s = excl + v;
    __syncthreads();
  }
  if (tid == 0) rowptr[N_NODES] = carry_s;
}

// ---------------- CSR fill ----------------
__global__ void k_fill(const int* __restrict__ src, const int* __restrict__ dst,
                       int* __restrict__ nextp, int* __restrict__ csr_src) {
  int e = blockIdx.x * 256 + threadIdx.x;
  if (e < N_EDGES) {
    int pos = atomicAdd(&nextp[dst[e]], 1);
    csr_src[pos] = src[e];
  }
}

// ---------------- fused edge-score + aggregation (bf16 kv, wave per node) ----------------
// writes att directly as bf16 hi/lo (feeds o-GEMM A side)
__global__ __launch_bounds__(256) void k_edgeagg(
    const int* __restrict__ rowptr, const int* __restrict__ csr_src,
    const float* __restrict__ q, const unsigned short* __restrict__ kv,
    short* __restrict__ att_h, short* __restrict__ att_l) {
  int lane = threadIdx.x & 63, wid = threadIdx.x >> 6;
  int n = blockIdx.x * 4 + wid;
  int beg = rowptr[n], end = rowptr[n + 1];
  float4 qv = *(const float4*)(q + (size_t)n * 256 + lane * 4);
  const unsigned short* kvl = kv + lane * 4;
  float a0 = 0.f, a1 = 0.f, a2 = 0.f, a3 = 0.f, z = 0.f;

#define EDGE_BODY(SRC)                                                        \
  {                                                                           \
    const unsigned short* rp = kvl + (size_t)(SRC) * 512;                     \
    uint2 ku = *(const uint2*)rp;                                             \
    uint2 vu = *(const uint2*)(rp + 256);                                     \
    float p = bflo(ku.x) * qv.x + bfhi(ku.x) * qv.y +                         \
              bflo(ku.y) * qv.z + bfhi(ku.y) * qv.w;                          \
    p += __shfl_xor(p, 1);                                                    \
    p += __shfl_xor(p, 2);                                                    \
    p += __shfl_xor(p, 4);                                                    \
    p += __shfl_xor(p, 8);                                                    \
    float e0 = __expf(fminf(fmaxf(p * 0.125f, -5.f), 5.f));                   \
    a0 = fmaf(e0, bflo(vu.x), a0);                                            \
    a1 = fmaf(e0, bfhi(vu.x), a1);                                            \
    a2 = fmaf(e0, bflo(vu.y), a2);                                            \
    a3 = fmaf(e0, bfhi(vu.y), a3);                                            \
    z += e0;                                                                  \
  }

  for (int base = beg; base < end; base += 64) {
    int idx = base + lane;
    int eid = (idx < end) ? csr_src[idx] : 0;
    int bs = min(64, end - base);
    int j = 0;
    for (; j + 4 <= bs; j += 4) {
      int s0 = __builtin_amdgcn_readlane(eid, j);
      int s1 = __builtin_amdgcn_readlane(eid, j + 1);
      int s2 = __builtin_amdgcn_readlane(eid, j + 2);
      int s3 = __builtin_amdgcn_readlane(eid, j + 3);
      EDGE_BODY(s0); EDGE_BODY(s1); EDGE_BODY(s2); EDGE_BODY(s3);
    }
    for (; j < bs; j++) {
      int s0 = __builtin_amdgcn_readlane(eid, j);
      EDGE_BODY(s0);
    }
  }
#undef EDGE_BODY

  float invz = 1.f / z;
  float rs[4] = {a0 * invz, a1 * invz, a2 * invz, a3 * invz};
  s16x4 h, l;
#pragma unroll
  for (int j = 0; j < 4; j++) {
    short hb = f2bf(rs[j]);
    h[j] = hb;
    l[j] = f2bf(rs[j] - bf2f(hb));
  }
  size_t base_o = (size_t)n * 256 + lane * 4;
  *(s16x4*)(att_h + base_o) = h;
  *(s16x4*)(att_l + base_o) = l;
}

// ---------------- fused BN-finalize + BN-apply + SE block (MFMA) ----------------
__global__ __launch_bounds__(256) void k_se2(
    const float* __restrict__ o,
    const float* __restrict__ bnsum, const float* __restrict__ bnsq,
    const float* __restrict__ gamma, const float* __restrict__ beta,
    const short* __restrict__ W1h, const short* __restrict__ W1l,
    const float* __restrict__ b1,
    const short* __restrict__ W2h, const short* __restrict__ W2l,
    const float* __restrict__ b2,
    const float* __restrict__ vin, float* __restrict__ out) {
  __shared__ __align__(16) short xh[64][264];
  __shared__ __align__(16) short xl[64][264];
  __shared__ __align__(16) short hh[64][72];
  __shared__ __align__(16) short hl[64][72];
  __shared__ float vt[64][256];
  __shared__ float scale_s[256], shift_s[256];

  int t = threadIdx.x;
  int lane = t & 63, w = t >> 6;
  int m0 = blockIdx.x * 64;

  // BN finalize (redundant per block, trivial)
  {
    float mean = bnsum[t] * (1.f / N_NODES);
    float var = bnsq[t] * (1.f / N_NODES) - mean * mean;
    float istd = rsqrtf(var + 1e-5f);
    float sc = gamma[t] * istd;
    scale_s[t] = sc;
    shift_s[t] = beta[t] - mean * sc;
  }
  __syncthreads();

  // ---- phase 0: x = relu6(o*scale+shift) -> bf16 split; stage v ----
  {
    int r = t >> 2;
    int cb = (t & 3) * 4;
    int gr = m0 + r;
    bool rok = gr < N_NODES;
#pragma unroll
    for (int p = 0; p < 16; p++) {
      int c = cb + p * 16;
      float4 ov = make_float4(0.f, 0.f, 0.f, 0.f), vv = ov;
      if (rok) {
        ov = *(const float4*)(o + (size_t)gr * 256 + c);
        vv = *(const float4*)(vin + (size_t)gr * 256 + c);
      }
      float xs[4];
      xs[0] = relu6f(fmaf(ov.x, scale_s[c + 0], shift_s[c + 0]));
      xs[1] = relu6f(fmaf(ov.y, scale_s[c + 1], shift_s[c + 1]));
      xs[2] = relu6f(fmaf(ov.z, scale_s[c + 2], shift_s[c + 2]));
      xs[3] = relu6f(fmaf(ov.w, scale_s[c + 3], shift_s[c + 3]));
#pragma unroll
      for (int j = 0; j < 4; j++) {
        short hb = f2bf(xs[j]);
        xh[r][c + j] = hb;
        xl[r][c + j] = f2bf(xs[j] - bf2f(hb));
      }
      *(float4*)&vt[r][c] = vv;
    }
  }
  __syncthreads();

  int fr = lane & 15, fq = lane >> 4;
  int kc = fq * 8;
  int arow = w * 16 + fr;

  // ---- phase 1: hidden = relu6(x @ W1 + b1) ----
  f32x4 acc1[4];
#pragma unroll
  for (int nf = 0; nf < 4; nf++) acc1[nf] = (f32x4){0.f, 0.f, 0.f, 0.f};
#pragma unroll
  for (int ks = 0; ks < 8; ks++) {
    s16x8 ah = *(const s16x8*)&xh[arow][ks * 32 + kc];
    s16x8 al = *(const s16x8*)&xl[arow][ks * 32 + kc];
#pragma unroll
    for (int nf = 0; nf < 4; nf++) {
      size_t bo_ = (size_t)(nf * 16 + fr) * 256 + ks * 32 + kc;
      s16x8 bh = *(const s16x8*)(W1h + bo_);
      s16x8 bl = *(const s16x8*)(W1l + bo_);
      acc1[nf] = __builtin_amdgcn_mfma_f32_16x16x32_bf16(ah, bh, acc1[nf], 0, 0, 0);
      acc1[nf] = __builtin_amdgcn_mfma_f32_16x16x32_bf16(al, bh, acc1[nf], 0, 0, 0);
      acc1[nf] = __builtin_amdgcn_mfma_f32_16x16x32_bf16(ah, bl, acc1[nf], 0, 0, 0);
    }
  }
#pragma unroll
  for (int nf = 0; nf < 4; nf++) {
    int n = nf * 16 + fr;
    float bv = b1[n];
#pragma unroll
    for (int j = 0; j < 4; j++) {
      int row = w * 16 + fq * 4 + j;
      float hv = relu6f(acc1[nf][j] + bv);
      short hb = f2bf(hv);
      hh[row][n] = hb;
      hl[row][n] = f2bf(hv - bf2f(hb));
    }
  }
  __syncthreads();

  // ---- phase 2: se = hidden @ W2 + b2; out = hswish(se)*x + v ----
  f32x4 acc2[16];
#pragma unroll
  for (int nf = 0; nf < 16; nf++) acc2[nf] = (f32x4){0.f, 0.f, 0.f, 0.f};
#pragma unroll
  for (int ks = 0; ks < 2; ks++) {
    s16x8 ah = *(const s16x8*)&hh[arow][ks * 32 + kc];
    s16x8 al = *(const s16x8*)&hl[arow][ks * 32 + kc];
#pragma unroll
    for (int nf = 0; nf < 16; nf++) {
      size_t bo_ = (size_t)(nf * 16 + fr) * 64 + ks * 32 + kc;
      s16x8 bh = *(const s16x8*)(W2h + bo_);
      s16x8 bl = *(const s16x8*)(W2l + bo_);
      acc2[nf] = __builtin_amdgcn_mfma_f32_16x16x32_bf16(ah, bh, acc2[nf], 0, 0, 0);
      acc2[nf] = __builtin_amdgcn_mfma_f32_16x16x32_bf16(al, bh, acc2[nf], 0, 0, 0);
      acc2[nf] = __builtin_amdgcn_mfma_f32_16x16x32_bf16(ah, bl, acc2[nf], 0, 0, 0);
    }
  }
#pragma unroll
  for (int nf = 0; nf < 16; nf++) {
    int col = nf * 16 + fr;
    float bv = b2[col];
#pragma unroll
    for (int j = 0; j < 4; j++) {
      int row = w * 16 + fq * 4 + j;
      int grow = m0 + row;
      if (grow < N_NODES) {
        float se = acc2[nf][j] + bv;
        float hs = se * relu6f(se + 3.f) * (1.f / 6.f);
        float xr = bf2f(xh[row][col]) + bf2f(xl[row][col]);
        out[(size_t)grow * 256 + col] = fmaf(hs, xr, vt[row][col]);
      }
    }
  }
}

extern "C" void kernel_launch(void* const* d_in, const int* in_sizes, int n_in,
                              void* d_out, int out_size, void* d_ws, size_t ws_size,
                              hipStream_t stream) {
  const float* v     = (const float*)d_in[0];
  const float* WQ    = (const float*)d_in[1];
  const float* bQ    = (const float*)d_in[2];
  const float* WK    = (const float*)d_in[3];
  const float* bK    = (const float*)d_in[4];
  const float* WV    = (const float*)d_in[5];
  const float* bV    = (const float*)d_in[6];
  const float* Wo    = (const float*)d_in[7];
  const float* bo    = (const float*)d_in[8];
  const float* W1    = (const float*)d_in[9];
  const float* b1    = (const float*)d_in[10];
  const float* W2    = (const float*)d_in[11];
  const float* b2    = (const float*)d_in[12];
  const float* gamma = (const float*)d_in[13];
  const float* beta  = (const float*)d_in[14];
  const int* srcI    = (const int*)d_in[15];
  const int* dstI    = (const int*)d_in[16];
  float* out = (float*)d_out;

  char* w = (char*)d_ws;
  size_t off = 0;
  auto take = [&](size_t bytes) {
    size_t o = off;
    off += (bytes + 255) & ~(size_t)255;
    return o;
  };
  // zeroed region (single memset): inc | outc | bnsum | bnsq | Zd
  int* inc      = (int*)(w + take(N_NODES * 4));
  int* outc     = (int*)(w + take(N_NODES * 4));
  float* bnsum  = (float*)(w + take(256 * 4));
  float* bnsq   = (float*)(w + take(256 * 4));
  double* Zd    = (double*)(w + take(8));
  size_t zero_span = off;
  float* logzf  = (float*)(w + take(4));
  float* q      = (float*)(w + take(ND * 4));
  unsigned short* kvb = (unsigned short*)(w + take((size_t)N_NODES * 512 * 2));
  short* Ahg    = (short*)(w + take(ND * 2));
  short* Alg    = (short*)(w + take(ND * 2));
  short* att_h  = (short*)(w + take(ND * 2));
  short* att_l  = (short*)(w + take(ND * 2));
  int* rowptr   = (int*)(w + take((N_NODES + 1) * 4));
  int* nextp    = (int*)(w + take(N_NODES * 4));
  int* csr_src  = (int*)(w + take((size_t)N_EDGES * 4));
  short* Wt_hi  = (short*)(w + take((size_t)4 * 65536 * 2));
  short* Wt_lo  = (short*)(w + take((size_t)4 * 65536 * 2));
  short* W1h    = (short*)(w + take((size_t)16384 * 2));
  short* W1l    = (short*)(w + take((size_t)16384 * 2));
  short* W2h    = (short*)(w + take((size_t)16384 * 2));
  short* W2l    = (short*)(w + take((size_t)16384 * 2));

  float* o = (float*)kvb;      // reuse: kv dead after edgeagg

  hipMemsetAsync(w, 0, zero_span, stream);

  k_wsplit<<<dim3(16, 4), dim3(256), 0, stream>>>(WQ, WK, WV, Wo, Wt_hi, Wt_lo);
  k_wsplit_t<<<dim3(4, 1), dim3(256), 0, stream>>>(W1, W1h, W1l, 256, 64);
  k_wsplit_t<<<dim3(1, 4), dim3(256), 0, stream>>>(W2, W2h, W2l, 64, 256);
  k_deg<<<dim3((N_EDGES + 255) / 256), dim3(256), 0, stream>>>(srcI, dstI, outc, inc);
  k_expsum<<<dim3((N_NODES + 255) / 256), dim3(256), 0, stream>>>(inc, outc, Zd);
  k_scan<<<dim3(1), dim3(1024), 0, stream>>>(inc, rowptr, nextp, Zd, logzf);
  k_fill<<<dim3((N_EDGES + 255) / 256), dim3(256), 0, stream>>>(srcI, dstI, nextp, csr_src);
  k_asplit<<<dim3((int)(ND / 4 / 256)), dim3(256), 0, stream>>>(v, inc, outc, logzf, Ahg, Alg);

  // q (fp32), k/vv (bf16 interleaved) = A @ {WQ,WK,WV} + b
  k_gemm_mfma<1><<<dim3(157, 2, 3), dim3(256), 0, stream>>>(
      Ahg, Alg, Wt_hi, Wt_lo, bQ, bK, bV, q, kvb, nullptr, nullptr, nullptr, N_NODES);

  k_edgeagg<<<dim3(N_NODES / 4), dim3(256), 0, stream>>>(rowptr, csr_src, q, kvb, att_h, att_l);

  // o = att @ Wo + bo, with fused BN column stats
  k_gemm_mfma<0><<<dim3(157, 2, 1), dim3(256), 0, stream>>>(
      att_h, att_l, Wt_hi + (size_t)3 * 65536, Wt_lo + (size_t)3 * 65536,
      bo, bo, bo, nullptr, nullptr, o, bnsum, bnsq, N_NODES);

  k_se2<<<dim3((N_NODES + 63) / 64), dim3(256), 0, stream>>>(
      o, bnsum, bnsq, gamma, beta, W1h, W1l, b1, W2h, W2l, b2, v, out);
}

// Round 12
// 284.130 us; speedup vs baseline: 1.9727x; 1.0325x over previous
//
#include <hip/hip_runtime.h>
#include <math.h>

#define N_NODES 10000
#define N_EDGES 320000
#define DIM 256
#define ND ((size_t)N_NODES * DIM)

typedef float f32x4 __attribute__((ext_vector_type(4)));
typedef short s16x8 __attribute__((ext_vector_type(8)));
typedef short s16x4 __attribute__((ext_vector_type(4)));

__device__ __forceinline__ float relu6f(float x) { return fminf(fmaxf(x, 0.f), 6.f); }

__device__ __forceinline__ short f2bf(float x) {
  unsigned u = __builtin_bit_cast(unsigned, x);
  unsigned r = (u + 0x7fffu + ((u >> 16) & 1u)) >> 16;
  return (short)r;
}
__device__ __forceinline__ float bf2f(short b) {
  unsigned u = ((unsigned)(unsigned short)b) << 16;
  return __builtin_bit_cast(float, u);
}
__device__ __forceinline__ float bflo(unsigned u) {
  return __builtin_bit_cast(float, u << 16);
}
__device__ __forceinline__ float bfhi(unsigned u) {
  return __builtin_bit_cast(float, u & 0xffff0000u);
}

// ---------------- combined prologue ----------------
// blocks 0..63   : transpose+split WQ/WK/WV/Wo (4 matrices x 16 tiles)
// blocks 64..67  : transpose+split W1 [256x64]
// blocks 68..71  : transpose+split W2 [64x256]
// blocks 72..1321: degree histograms (1250 blocks x 256 threads)
__global__ __launch_bounds__(256) void k_prologue(
    const float* __restrict__ WQ, const float* __restrict__ WK,
    const float* __restrict__ WV, const float* __restrict__ Wo,
    const float* __restrict__ W1, const float* __restrict__ W2,
    short* __restrict__ Wt_hi, short* __restrict__ Wt_lo,
    short* __restrict__ W1h, short* __restrict__ W1l,
    short* __restrict__ W2h, short* __restrict__ W2l,
    const int* __restrict__ src, const int* __restrict__ dst,
    int* __restrict__ outc, int* __restrict__ inc) {
  __shared__ float tile[64][65];
  int bid = blockIdx.x, t = threadIdx.x;
  if (bid < 72) {
    const float* W;
    short *hi, *lo;
    int K, N, tk, tn;
    if (bid < 64) {
      int mat = bid >> 4, tl = bid & 15;
      W = (mat == 0) ? WQ : (mat == 1) ? WK : (mat == 2) ? WV : Wo;
      hi = Wt_hi + (size_t)mat * 65536;
      lo = Wt_lo + (size_t)mat * 65536;
      K = 256; N = 256;
      tk = (tl >> 2) * 64; tn = (tl & 3) * 64;
    } else if (bid < 68) {
      W = W1; hi = W1h; lo = W1l;
      K = 256; N = 64;
      tk = (bid - 64) * 64; tn = 0;
    } else {
      W = W2; hi = W2h; lo = W2l;
      K = 64; N = 256;
      tk = 0; tn = (bid - 68) * 64;
    }
    int r = t >> 4, c4 = (t & 15) * 4;
#pragma unroll
    for (int p = 0; p < 4; p++) {
      float4 v4 = *(const float4*)(W + (size_t)(tk + p * 16 + r) * N + tn + c4);
      tile[p * 16 + r][c4 + 0] = v4.x;
      tile[p * 16 + r][c4 + 1] = v4.y;
      tile[p * 16 + r][c4 + 2] = v4.z;
      tile[p * 16 + r][c4 + 3] = v4.w;
    }
    __syncthreads();
    int nl = t >> 2, q = t & 3;
    s16x8 h0, h1, l0, l1;
#pragma unroll
    for (int j = 0; j < 8; j++) {
      float x = tile[q * 16 + j][nl];
      short hb = f2bf(x);
      h0[j] = hb; l0[j] = f2bf(x - bf2f(hb));
    }
#pragma unroll
    for (int j = 0; j < 8; j++) {
      float x = tile[q * 16 + 8 + j][nl];
      short hb = f2bf(x);
      h1[j] = hb; l1[j] = f2bf(x - bf2f(hb));
    }
    size_t base = (size_t)(tn + nl) * K + tk + q * 16;
    *(s16x8*)(hi + base) = h0;
    *(s16x8*)(hi + base + 8) = h1;
    *(s16x8*)(lo + base) = l0;
    *(s16x8*)(lo + base + 8) = l1;
  } else {
    int e = (bid - 72) * 256 + t;
    if (e < N_EDGES) {
      atomicAdd(&outc[src[e]], 1);
      atomicAdd(&inc[dst[e]], 1);
    }
  }
}

// ---------------- exclusive scan + softmax logZ (single block) ----------------
__global__ void k_scan(const int* __restrict__ inc, const int* __restrict__ outc,
                       int* __restrict__ rowptr, int* __restrict__ nextp,
                       float* __restrict__ logzf) {
  __shared__ int wsum[16];
  __shared__ double dsum[16];
  __shared__ int carry_s;
  int tid = threadIdx.x, lane = tid & 63, wid = tid >> 6;

  // exp-sum of degrees in double
  double e = 0.0;
  for (int i = tid; i < N_NODES; i += 1024) e += exp((double)(inc[i] + outc[i]));
#pragma unroll
  for (int off = 1; off < 64; off <<= 1) e += __shfl_xor(e, off);
  if (lane == 0) dsum[wid] = e;
  __syncthreads();
  if (tid == 0) {
    double Z = 0.0;
#pragma unroll
    for (int i = 0; i < 16; i++) Z += dsum[i];
    logzf[0] = (float)log(Z);
    carry_s = 0;
  }
  __syncthreads();

  // exclusive scan of in-degree
  for (int base = 0; base < N_NODES; base += 1024) {
    int i = base + tid;
    int v = (i < N_NODES) ? inc[i] : 0;
    int x = v;
#pragma unroll
    for (int off = 1; off < 64; off <<= 1) {
      int t = __shfl_up(x, off);
      if (lane >= off) x += t;
    }
    if (lane == 63) wsum[wid] = x;
    __syncthreads();
    if (wid == 0 && lane < 16) {
      int wv = wsum[lane];
#pragma unroll
      for (int off = 1; off < 16; off <<= 1) {
        int t = __shfl_up(wv, off);
        if (lane >= off) wv += t;
      }
      wsum[lane] = wv;
    }
    __syncthreads();
    int carry = carry_s;
    int wadd = (wid > 0) ? wsum[wid - 1] : 0;
    int excl = carry + wadd + x - v;
    if (i < N_NODES) {
      rowptr[i] = excl;
      nextp[i] = excl;
    }
    __syncthreads();
    if (tid == 1023) carry_s = excl + v;
    __syncthreads();
  }
  if (tid == 0) rowptr[N_NODES] = carry_s;
}

// ---------------- combined CSR fill + A presplit ----------------
// 2500 blocks: all do asplit (covers ND exactly); blocks 0..1249 also fill CSR.
__global__ __launch_bounds__(256) void k_fillsplit(
    const int* __restrict__ src, const int* __restrict__ dst,
    int* __restrict__ nextp, int* __restrict__ csr_src,
    const float* __restrict__ v, const int* __restrict__ inc,
    const int* __restrict__ outc, const float* __restrict__ logzf,
    short* __restrict__ Ahg, short* __restrict__ Alg) {
  int bid = blockIdx.x, t = threadIdx.x;
  int e = bid * 256 + t;
  if (e < N_EDGES) {
    int pos = atomicAdd(&nextp[dst[e]], 1);
    csr_src[pos] = src[e];
  }
  size_t idx = ((size_t)bid * 256 + t) * 4;
  int row = (int)(idx >> 8);
  float c = __expf((float)(inc[row] + outc[row]) - logzf[0]);
  float4 x = *(const float4*)(v + idx);
  float xs[4] = {x.x * c, x.y * c, x.z * c, x.w * c};
  s16x4 h, l;
#pragma unroll
  for (int j = 0; j < 4; j++) {
    short hb = f2bf(xs[j]);
    h[j] = hb;
    l[j] = f2bf(xs[j] - bf2f(hb));
  }
  *(s16x4*)(Ahg + idx) = h;
  *(s16x4*)(Alg + idx) = l;
}

// ---------------- bf16-split MFMA GEMM (A pre-split in global) ----------------
// KVMODE=1: z=0 -> Qout fp32; z=1 -> KV bf16 cols 0..255; z=2 -> KV cols 256..511
// KVMODE=0: z=0 -> Cbase fp32, + BN column sums via atomics
template <int KVMODE>
__global__ __launch_bounds__(256) void k_gemm_mfma(
    const short* __restrict__ Ahg, const short* __restrict__ Alg,
    const short* __restrict__ Whi, const short* __restrict__ Wlo,
    const float* __restrict__ b0, const float* __restrict__ b1,
    const float* __restrict__ b2, float* __restrict__ Qout,
    unsigned short* __restrict__ KVout, float* __restrict__ Cbase,
    float* __restrict__ bnsum, float* __restrict__ bnsq, int M) {
  const float* bias = (blockIdx.z == 0) ? b0 : (blockIdx.z == 1) ? b1 : b2;
  const short* whi = Whi + (size_t)blockIdx.z * 65536;
  const short* wlo = Wlo + (size_t)blockIdx.z * 65536;

  __shared__ __align__(16) short Ah[64][40];
  __shared__ __align__(16) short Al[64][40];
  __shared__ __align__(16) short Bh[128][40];
  __shared__ __align__(16) short Bl[128][40];

  int tid = threadIdx.x;
  int lane = tid & 63, wid = tid >> 6;
  int wm = wid >> 1, wn = wid & 1;
  int m0 = blockIdx.x * 64;
  int n0g = blockIdx.y * 128;

  f32x4 acc[2][4];
#pragma unroll
  for (int i = 0; i < 2; i++)
#pragma unroll
    for (int j = 0; j < 4; j++) acc[i][j] = (f32x4){0.f, 0.f, 0.f, 0.f};

  int sa_row = tid >> 2, sa_seg = tid & 3;
  int sb_row = tid >> 1, sb_seg = tid & 1;
  const s16x8 zero8 = {0, 0, 0, 0, 0, 0, 0, 0};

  for (int k0 = 0; k0 < 256; k0 += 32) {
    __syncthreads();
    {
      int m = m0 + sa_row;
      s16x8 h = zero8, l = zero8;
      if (m < M) {
        size_t ga = (size_t)m * 256 + k0 + sa_seg * 8;
        h = *(const s16x8*)(Ahg + ga);
        l = *(const s16x8*)(Alg + ga);
      }
      *(s16x8*)&Ah[sa_row][sa_seg * 8] = h;
      *(s16x8*)&Al[sa_row][sa_seg * 8] = l;
    }
    {
      size_t gb = (size_t)(n0g + sb_row) * 256 + k0 + sb_seg * 16;
      *(s16x8*)&Bh[sb_row][sb_seg * 16] = *(const s16x8*)(whi + gb);
      *(s16x8*)&Bh[sb_row][sb_seg * 16 + 8] = *(const s16x8*)(whi + gb + 8);
      *(s16x8*)&Bl[sb_row][sb_seg * 16] = *(const s16x8*)(wlo + gb);
      *(s16x8*)&Bl[sb_row][sb_seg * 16 + 8] = *(const s16x8*)(wlo + gb + 8);
    }
    __syncthreads();
    int arow0 = wm * 32 + (lane & 15);
    int kc = (lane >> 4) * 8;
    s16x8 ah[2], al[2], bh[4], bl[4];
#pragma unroll
    for (int mf = 0; mf < 2; mf++) {
      ah[mf] = *(const s16x8*)&Ah[arow0 + mf * 16][kc];
      al[mf] = *(const s16x8*)&Al[arow0 + mf * 16][kc];
    }
    int brow0 = wn * 64 + (lane & 15);
#pragma unroll
    for (int nf = 0; nf < 4; nf++) {
      bh[nf] = *(const s16x8*)&Bh[brow0 + nf * 16][kc];
      bl[nf] = *(const s16x8*)&Bl[brow0 + nf * 16][kc];
    }
#pragma unroll
    for (int mf = 0; mf < 2; mf++)
#pragma unroll
      for (int nf = 0; nf < 4; nf++) {
        acc[mf][nf] = __builtin_amdgcn_mfma_f32_16x16x32_bf16(ah[mf], bh[nf], acc[mf][nf], 0, 0, 0);
        acc[mf][nf] = __builtin_amdgcn_mfma_f32_16x16x32_bf16(al[mf], bh[nf], acc[mf][nf], 0, 0, 0);
        acc[mf][nf] = __builtin_amdgcn_mfma_f32_16x16x32_bf16(ah[mf], bl[nf], acc[mf][nf], 0, 0, 0);
      }
  }

  int colq = lane & 15, rowq = (lane >> 4) * 4;
  if (KVMODE == 1) {
    bool isq = (blockIdx.z == 0);
    int kvoff = (blockIdx.z == 1) ? 0 : 256;
#pragma unroll
    for (int mf = 0; mf < 2; mf++) {
#pragma unroll
      for (int nf = 0; nf < 4; nf++) {
        int n = wn * 64 + nf * 16 + colq;
        float bv = bias[n0g + n];
#pragma unroll
        for (int j = 0; j < 4; j++) {
          int m = m0 + wm * 32 + mf * 16 + rowq + j;
          if (m >= M) continue;
          float val = acc[mf][nf][j] + bv;
          if (isq) Qout[(size_t)m * 256 + n0g + n] = val;
          else KVout[(size_t)m * 512 + kvoff + n0g + n] = (unsigned short)f2bf(val);
        }
      }
    }
  } else {
    float cs[4], cq[4];
#pragma unroll
    for (int nf = 0; nf < 4; nf++) { cs[nf] = 0.f; cq[nf] = 0.f; }
#pragma unroll
    for (int nf = 0; nf < 4; nf++) {
      int n = wn * 64 + nf * 16 + colq;
      float bv = bias[n0g + n];
#pragma unroll
      for (int mf = 0; mf < 2; mf++) {
#pragma unroll
        for (int j = 0; j < 4; j++) {
          int m = m0 + wm * 32 + mf * 16 + rowq + j;
          if (m >= M) continue;
          float val = acc[mf][nf][j] + bv;
          Cbase[(size_t)m * 256 + n0g + n] = val;
          cs[nf] += val;
          cq[nf] = fmaf(val, val, cq[nf]);
        }
      }
    }
#pragma unroll
    for (int nf = 0; nf < 4; nf++) {
      float s = cs[nf], qq = cq[nf];
      s += __shfl_xor(s, 16); s += __shfl_xor(s, 32);
      qq += __shfl_xor(qq, 16); qq += __shfl_xor(qq, 32);
      if (lane < 16) {
        int n = n0g + wn * 64 + nf * 16 + lane;
        atomicAdd(&bnsum[n], s);
        atomicAdd(&bnsq[n], qq);
      }
    }
  }
}

// ---------------- fused edge-score + aggregation (bf16 kv, wave per node) ----------------
__global__ __launch_bounds__(256) void k_edgeagg(
    const int* __restrict__ rowptr, const int* __restrict__ csr_src,
    const float* __restrict__ q, const unsigned short* __restrict__ kv,
    short* __restrict__ att_h, short* __restrict__ att_l) {
  int lane = threadIdx.x & 63, wid = threadIdx.x >> 6;
  int n = blockIdx.x * 4 + wid;
  int beg = rowptr[n], end = rowptr[n + 1];
  float4 qv = *(const float4*)(q + (size_t)n * 256 + lane * 4);
  const unsigned short* kvl = kv + lane * 4;
  float a0 = 0.f, a1 = 0.f, a2 = 0.f, a3 = 0.f, z = 0.f;

#define EDGE_BODY(SRC)                                                        \
  {                                                                           \
    const unsigned short* rp = kvl + (size_t)(SRC) * 512;                     \
    uint2 ku = *(const uint2*)rp;                                             \
    uint2 vu = *(const uint2*)(rp + 256);                                     \
    float p = bflo(ku.x) * qv.x + bfhi(ku.x) * qv.y +                         \
              bflo(ku.y) * qv.z + bfhi(ku.y) * qv.w;                          \
    p += __shfl_xor(p, 1);                                                    \
    p += __shfl_xor(p, 2);                                                    \
    p += __shfl_xor(p, 4);                                                    \
    p += __shfl_xor(p, 8);                                                    \
    float e0 = __expf(fminf(fmaxf(p * 0.125f, -5.f), 5.f));                   \
    a0 = fmaf(e0, bflo(vu.x), a0);                                            \
    a1 = fmaf(e0, bfhi(vu.x), a1);                                            \
    a2 = fmaf(e0, bflo(vu.y), a2);                                            \
    a3 = fmaf(e0, bfhi(vu.y), a3);                                            \
    z += e0;                                                                  \
  }

  for (int base = beg; base < end; base += 64) {
    int idx = base + lane;
    int eid = (idx < end) ? csr_src[idx] : 0;
    int bs = min(64, end - base);
    int j = 0;
    for (; j + 4 <= bs; j += 4) {
      int s0 = __builtin_amdgcn_readlane(eid, j);
      int s1 = __builtin_amdgcn_readlane(eid, j + 1);
      int s2 = __builtin_amdgcn_readlane(eid, j + 2);
      int s3 = __builtin_amdgcn_readlane(eid, j + 3);
      EDGE_BODY(s0); EDGE_BODY(s1); EDGE_BODY(s2); EDGE_BODY(s3);
    }
    for (; j < bs; j++) {
      int s0 = __builtin_amdgcn_readlane(eid, j);
      EDGE_BODY(s0);
    }
  }
#undef EDGE_BODY

  float invz = 1.f / z;
  float rs[4] = {a0 * invz, a1 * invz, a2 * invz, a3 * invz};
  s16x4 h, l;
#pragma unroll
  for (int j = 0; j < 4; j++) {
    short hb = f2bf(rs[j]);
    h[j] = hb;
    l[j] = f2bf(rs[j] - bf2f(hb));
  }
  size_t base_o = (size_t)n * 256 + lane * 4;
  *(s16x4*)(att_h + base_o) = h;
  *(s16x4*)(att_l + base_o) = l;
}

// ---------------- fused BN-finalize + BN-apply + SE block (MFMA) ----------------
__global__ __launch_bounds__(256) void k_se2(
    const float* __restrict__ o,
    const float* __restrict__ bnsum, const float* __restrict__ bnsq,
    const float* __restrict__ gamma, const float* __restrict__ beta,
    const short* __restrict__ W1h, const short* __restrict__ W1l,
    const float* __restrict__ b1,
    const short* __restrict__ W2h, const short* __restrict__ W2l,
    const float* __restrict__ b2,
    const float* __restrict__ vin, float* __restrict__ out) {
  __shared__ __align__(16) short xh[64][264];
  __shared__ __align__(16) short xl[64][264];
  __shared__ __align__(16) short hh[64][72];
  __shared__ __align__(16) short hl[64][72];
  __shared__ float vt[64][256];
  __shared__ float scale_s[256], shift_s[256];

  int t = threadIdx.x;
  int lane = t & 63, w = t >> 6;
  int m0 = blockIdx.x * 64;

  {
    float mean = bnsum[t] * (1.f / N_NODES);
    float var = bnsq[t] * (1.f / N_NODES) - mean * mean;
    float istd = rsqrtf(var + 1e-5f);
    float sc = gamma[t] * istd;
    scale_s[t] = sc;
    shift_s[t] = beta[t] - mean * sc;
  }
  __syncthreads();

  {
    int r = t >> 2;
    int cb = (t & 3) * 4;
    int gr = m0 + r;
    bool rok = gr < N_NODES;
#pragma unroll
    for (int p = 0; p < 16; p++) {
      int c = cb + p * 16;
      float4 ov = make_float4(0.f, 0.f, 0.f, 0.f), vv = ov;
      if (rok) {
        ov = *(const float4*)(o + (size_t)gr * 256 + c);
        vv = *(const float4*)(vin + (size_t)gr * 256 + c);
      }
      float xs[4];
      xs[0] = relu6f(fmaf(ov.x, scale_s[c + 0], shift_s[c + 0]));
      xs[1] = relu6f(fmaf(ov.y, scale_s[c + 1], shift_s[c + 1]));
      xs[2] = relu6f(fmaf(ov.z, scale_s[c + 2], shift_s[c + 2]));
      xs[3] = relu6f(fmaf(ov.w, scale_s[c + 3], shift_s[c + 3]));
#pragma unroll
      for (int j = 0; j < 4; j++) {
        short hb = f2bf(xs[j]);
        xh[r][c + j] = hb;
        xl[r][c + j] = f2bf(xs[j] - bf2f(hb));
      }
      *(float4*)&vt[r][c] = vv;
    }
  }
  __syncthreads();

  int fr = lane & 15, fq = lane >> 4;
  int kc = fq * 8;
  int arow = w * 16 + fr;

  f32x4 acc1[4];
#pragma unroll
  for (int nf = 0; nf < 4; nf++) acc1[nf] = (f32x4){0.f, 0.f, 0.f, 0.f};
#pragma unroll
  for (int ks = 0; ks < 8; ks++) {
    s16x8 ah = *(const s16x8*)&xh[arow][ks * 32 + kc];
    s16x8 al = *(const s16x8*)&xl[arow][ks * 32 + kc];
#pragma unroll
    for (int nf = 0; nf < 4; nf++) {
      size_t bo_ = (size_t)(nf * 16 + fr) * 256 + ks * 32 + kc;
      s16x8 bh = *(const s16x8*)(W1h + bo_);
      s16x8 bl = *(const s16x8*)(W1l + bo_);
      acc1[nf] = __builtin_amdgcn_mfma_f32_16x16x32_bf16(ah, bh, acc1[nf], 0, 0, 0);
      acc1[nf] = __builtin_amdgcn_mfma_f32_16x16x32_bf16(al, bh, acc1[nf], 0, 0, 0);
      acc1[nf] = __builtin_amdgcn_mfma_f32_16x16x32_bf16(ah, bl, acc1[nf], 0, 0, 0);
    }
  }
#pragma unroll
  for (int nf = 0; nf < 4; nf++) {
    int n = nf * 16 + fr;
    float bv = b1[n];
#pragma unroll
    for (int j = 0; j < 4; j++) {
      int row = w * 16 + fq * 4 + j;
      float hv = relu6f(acc1[nf][j] + bv);
      short hb = f2bf(hv);
      hh[row][n] = hb;
      hl[row][n] = f2bf(hv - bf2f(hb));
    }
  }
  __syncthreads();

  f32x4 acc2[16];
#pragma unroll
  for (int nf = 0; nf < 16; nf++) acc2[nf] = (f32x4){0.f, 0.f, 0.f, 0.f};
#pragma unroll
  for (int ks = 0; ks < 2; ks++) {
    s16x8 ah = *(const s16x8*)&hh[arow][ks * 32 + kc];
    s16x8 al = *(const s16x8*)&hl[arow][ks * 32 + kc];
#pragma unroll
    for (int nf = 0; nf < 16; nf++) {
      size_t bo_ = (size_t)(nf * 16 + fr) * 64 + ks * 32 + kc;
      s16x8 bh = *(const s16x8*)(W2h + bo_);
      s16x8 bl = *(const s16x8*)(W2l + bo_);
      acc2[nf] = __builtin_amdgcn_mfma_f32_16x16x32_bf16(ah, bh, acc2[nf], 0, 0, 0);
      acc2[nf] = __builtin_amdgcn_mfma_f32_16x16x32_bf16(al, bh, acc2[nf], 0, 0, 0);
      acc2[nf] = __builtin_amdgcn_mfma_f32_16x16x32_bf16(ah, bl, acc2[nf], 0, 0, 0);
    }
  }
#pragma unroll
  for (int nf = 0; nf < 16; nf++) {
    int col = nf * 16 + fr;
    float bv = b2[col];
#pragma unroll
    for (int j = 0; j < 4; j++) {
      int row = w * 16 + fq * 4 + j;
      int grow = m0 + row;
      if (grow < N_NODES) {
        float se = acc2[nf][j] + bv;
        float hs = se * relu6f(se + 3.f) * (1.f / 6.f);
        float xr = bf2f(xh[row][col]) + bf2f(xl[row][col]);
        out[(size_t)grow * 256 + col] = fmaf(hs, xr, vt[row][col]);
      }
    }
  }
}

extern "C" void kernel_launch(void* const* d_in, const int* in_sizes, int n_in,
                              void* d_out, int out_size, void* d_ws, size_t ws_size,
                              hipStream_t stream) {
  const float* v     = (const float*)d_in[0];
  const float* WQ    = (const float*)d_in[1];
  const float* bQ    = (const float*)d_in[2];
  const float* WK    = (const float*)d_in[3];
  const float* bK    = (const float*)d_in[4];
  const float* WV    = (const float*)d_in[5];
  const float* bV    = (const float*)d_in[6];
  const float* Wo    = (const float*)d_in[7];
  const float* bo    = (const float*)d_in[8];
  const float* W1    = (const float*)d_in[9];
  const float* b1    = (const float*)d_in[10];
  const float* W2    = (const float*)d_in[11];
  const float* b2    = (const float*)d_in[12];
  const float* gamma = (const float*)d_in[13];
  const float* beta  = (const float*)d_in[14];
  const int* srcI    = (const int*)d_in[15];
  const int* dstI    = (const int*)d_in[16];
  float* out = (float*)d_out;

  char* w = (char*)d_ws;
  size_t off = 0;
  auto take = [&](size_t bytes) {
    size_t o = off;
    off += (bytes + 255) & ~(size_t)255;
    return o;
  };
  // zeroed region (single memset): inc | outc | bnsum | bnsq
  int* inc      = (int*)(w + take(N_NODES * 4));
  int* outc     = (int*)(w + take(N_NODES * 4));
  float* bnsum  = (float*)(w + take(256 * 4));
  float* bnsq   = (float*)(w + take(256 * 4));
  size_t zero_span = off;
  float* logzf  = (float*)(w + take(4));
  float* q      = (float*)(w + take(ND * 4));
  unsigned short* kvb = (unsigned short*)(w + take((size_t)N_NODES * 512 * 2));
  short* Ahg    = (short*)(w + take(ND * 2));
  short* Alg    = (short*)(w + take(ND * 2));
  short* att_h  = (short*)(w + take(ND * 2));
  short* att_l  = (short*)(w + take(ND * 2));
  int* rowptr   = (int*)(w + take((N_NODES + 1) * 4));
  int* nextp    = (int*)(w + take(N_NODES * 4));
  int* csr_src  = (int*)(w + take((size_t)N_EDGES * 4));
  short* Wt_hi  = (short*)(w + take((size_t)4 * 65536 * 2));
  short* Wt_lo  = (short*)(w + take((size_t)4 * 65536 * 2));
  short* W1h    = (short*)(w + take((size_t)16384 * 2));
  short* W1l    = (short*)(w + take((size_t)16384 * 2));
  short* W2h    = (short*)(w + take((size_t)16384 * 2));
  short* W2l    = (short*)(w + take((size_t)16384 * 2));

  float* o = (float*)kvb;      // reuse: kv dead after edgeagg

  hipMemsetAsync(w, 0, zero_span, stream);

  k_prologue<<<dim3(1322), dim3(256), 0, stream>>>(
      WQ, WK, WV, Wo, W1, W2, Wt_hi, Wt_lo, W1h, W1l, W2h, W2l,
      srcI, dstI, outc, inc);

  k_scan<<<dim3(1), dim3(1024), 0, stream>>>(inc, outc, rowptr, nextp, logzf);

  k_fillsplit<<<dim3(2500), dim3(256), 0, stream>>>(
      srcI, dstI, nextp, csr_src, v, inc, outc, logzf, Ahg, Alg);

  // q (fp32), k/vv (bf16 interleaved) = A @ {WQ,WK,WV} + b
  k_gemm_mfma<1><<<dim3(157, 2, 3), dim3(256), 0, stream>>>(
      Ahg, Alg, Wt_hi, Wt_lo, bQ, bK, bV, q, kvb, nullptr, nullptr, nullptr, N_NODES);

  k_edgeagg<<<dim3(N_NODES / 4), dim3(256), 0, stream>>>(rowptr, csr_src, q, kvb, att_h, att_l);

  // o = att @ Wo + bo, with fused BN column stats
  k_gemm_mfma<0><<<dim3(157, 2, 1), dim3(256), 0, stream>>>(
      att_h, att_l, Wt_hi + (size_t)3 * 65536, Wt_lo + (size_t)3 * 65536,
      bo, bo, bo, nullptr, nullptr, o, bnsum, bnsq, N_NODES);

  k_se2<<<dim3((N_NODES + 63) / 64), dim3(256), 0, stream>>>(
      o, bnsum, bnsq, gamma, beta, W1h, W1l, b1, W2h, W2l, b2, v, out);
}